// Round 15
// baseline (351.411 us; speedup 1.0000x reference)
//
#include <hip/hip_runtime.h>
#include <math.h>

#define NB 16
#define N0 4096
#define NE 524288
#define CAPE 768

// ---------------- CSR build (layer 0, atomic int cursor only) ----------------

static __global__ void k_count(const int* __restrict__ dst, int* __restrict__ cnt) {
  int e = blockIdx.x * 256 + threadIdx.x;
  if (e >= NE) return;
  atomicAdd(&cnt[dst[e]], 1);
}

static __global__ void k_fill0(const int* __restrict__ src, const int* __restrict__ dst,
                               int* __restrict__ cursor, int* __restrict__ list) {
  int e = blockIdx.x * 256 + threadIdx.x;
  if (e >= NE) return;
  int d = dst[e];
  int slot = atomicAdd(&cursor[d], 1);
  list[slot] = src[e];
}

// ---------------- exclusive scan (scan1 + scan3-with-inline-bsum-prefix) ----------------

static __global__ void k_scan1(const int* __restrict__ in, int* __restrict__ out,
                               int* __restrict__ bsum, int n) {
  __shared__ int ts[256];
  int base = blockIdx.x * 1024 + threadIdx.x * 4;
  int a0 = (base + 0 < n) ? in[base + 0] : 0;
  int a1 = (base + 1 < n) ? in[base + 1] : 0;
  int a2 = (base + 2 < n) ? in[base + 2] : 0;
  int a3 = (base + 3 < n) ? in[base + 3] : 0;
  int s = a0 + a1 + a2 + a3;
  ts[threadIdx.x] = s;
  __syncthreads();
  for (int off = 1; off < 256; off <<= 1) {
    int v = (threadIdx.x >= off) ? ts[threadIdx.x - off] : 0;
    __syncthreads();
    ts[threadIdx.x] += v;
    __syncthreads();
  }
  int excl = ts[threadIdx.x] - s;
  if (base + 0 < n) out[base + 0] = excl;
  excl += a0;
  if (base + 1 < n) out[base + 1] = excl;
  excl += a1;
  if (base + 2 < n) out[base + 2] = excl;
  excl += a2;
  if (base + 3 < n) out[base + 3] = excl;
  if (threadIdx.x == 255) bsum[blockIdx.x] = ts[255];
}

static __global__ void k_scan3(int* __restrict__ out, int* __restrict__ out2,
                               const int* __restrict__ bsum, int n, int nblk) {
  __shared__ int sb[64];
  int t = threadIdx.x;
  if (t < 64) {
    int v = (t < nblk) ? bsum[t] : 0;
    int p = v;
    for (int off = 1; off < 64; off <<= 1) {
      int u = __shfl_up(p, off);
      if (t >= off) p += u;
    }
    sb[t] = p - v;
  }
  __syncthreads();
  int i = blockIdx.x * 256 + t;
  if (i < n) {
    int v = out[i] + sb[i >> 10];
    out[i] = v;
    if (out2) out2[i] = v;
  }
}

// ---------------- CSR compaction fill (pools 0,1 only) ----------------

static __global__ void k_newfill(const int* __restrict__ perm, const int* __restrict__ offs,
                                 const int* __restrict__ cnt, const int* __restrict__ list,
                                 const int* __restrict__ newidx, const int* __restrict__ noffs,
                                 int* __restrict__ nlist, int newn) {
  int nn = blockIdx.x * 256 + threadIdx.x;
  if (nn >= newn) return;
  int old = perm[nn];
  int st = offs[old], c = cnt[old];
  int pos = noffs[nn];
  for (int j = 0; j < c; ++j) {
    int s2 = newidx[list[st + j]];
    if (s2 >= 0) nlist[pos++] = s2;
  }
}

// ---------------- fused pnorm (blocks 0-5) + weight prep (blocks 6-12) ----------------

static __global__ void k_pw(const float* __restrict__ p0, const float* __restrict__ p1,
                            const float* __restrict__ p2, const float* __restrict__ p3,
                            const float* __restrict__ p4, const float* __restrict__ p5,
                            const float* __restrict__ w0, const float* __restrict__ w1,
                            const float* __restrict__ w2, const float* __restrict__ w3,
                            const float* __restrict__ w4, const float* __restrict__ w5,
                            const float* __restrict__ w6, float* __restrict__ pnbuf,
                            float* __restrict__ wp) {
  if (blockIdx.x < 6) {
    if (threadIdx.x >= 64) return;
    const float* pp = p0;
    switch (blockIdx.x) {
      case 1: pp = p1; break;
      case 2: pp = p2; break;
      case 3: pp = p3; break;
      case 4: pp = p4; break;
      case 5: pp = p5; break;
      default: break;
    }
    double v = (double)pp[threadIdx.x];
    v *= v;
#pragma unroll
    for (int off = 1; off < 64; off <<= 1) v += __shfl_xor(v, off);
    if (threadIdx.x == 0) pnbuf[blockIdx.x] = (float)(1.0 / sqrt(v));
  } else {
    int wi = blockIdx.x - 6;
    const float* src = w0;
    switch (wi) {
      case 1: src = w1; break;
      case 2: src = w2; break;
      case 3: src = w3; break;
      case 4: src = w4; break;
      case 5: src = w5; break;
      case 6: src = w6; break;
      default: break;
    }
    float* dst = wp + (size_t)wi * 4096;
    const float4* w4p = (const float4*)src;
    for (int i4 = threadIdx.x; i4 < 1024; i4 += 256) {
      int o = i4 >> 4, db = (i4 & 15) << 2;
      float4 W = w4p[i4];
      float Wv[4] = {W.x, W.y, W.z, W.w};
      int og = o >> 2, o3 = o & 3;
#pragma unroll
      for (int j = 0; j < 4; ++j) {
        int d = db + j;
        dst[(d << 6) + (((og ^ (d & 15)) << 2) | o3)] = Wv[j];
      }
    }
  }
}

// ---------------- SAGE layer 0 (DIN=2): fused mean (64 nodes/block, 1 thread/node)
// + linear + relu + score. 1024 threads: phase1 t<64 one node each; phase2 16 waves x 4 nodes.

static __global__ __launch_bounds__(1024) void k_sage0(
    const float* __restrict__ x, const int* __restrict__ offs, const int* __restrict__ cnt,
    const int* __restrict__ list, const float* __restrict__ wl, const float* __restrict__ blv,
    const float* __restrict__ wr, const float* __restrict__ pvec,
    const float* __restrict__ pnbuf, float* __restrict__ h, float* __restrict__ score) {
  __shared__ float wlT[2][65], wrT[2][65];
  __shared__ float msh[64][2];
  int t = threadIdx.x;
  if (t < 128) {
    int o = t >> 1, d = t & 1;
    wlT[d][o] = wl[o * 2 + d];
    wrT[d][o] = wr[o * 2 + d];
  }
  if (t < 64) {
    int v = blockIdx.x * 64 + t;
    int st = offs[v], c = cnt[v];
    float s0 = 0.f, s1 = 0.f;
    for (int j = 0; j < c; ++j) {
      int s = list[st + j];
      s0 += x[s * 2 + 0];
      s1 += x[s * 2 + 1];
    }
    float inv = 1.0f / fmaxf((float)c, 1.0f);
    msh[t][0] = s0 * inv;
    msh[t][1] = s1 * inv;
  }
  __syncthreads();
  int o = t & 63, w = t >> 6;  // 16 waves
  float pn = pnbuf[0];
  float psl = pvec[o];
#pragma unroll
  for (int r = 0; r < 4; ++r) {
    int node = w * 4 + r;
    int v = blockIdx.x * 64 + node;
    float acc = blv[o] + msh[node][0] * wlT[0][o] + msh[node][1] * wlT[1][o] +
                x[v * 2 + 0] * wrT[0][o] + x[v * 2 + 1] * wrT[1][o];
    float hval = fmaxf(acc, 0.0f);
    h[(size_t)v * 64 + o] = hval;
    double sc = (double)hval * (double)psl;
#pragma unroll
    for (int off = 1; off < 64; off <<= 1) sc += __shfl_xor(sc, off);
    if (o == 0) score[v] = (float)sc * pn;
  }
}

// Fused SAGE DIN=64, 512 threads, 32-node tile (4 blocks/CU): XCD swizzle, LDS
// list staging, branchless 4-way ILP gather, 1x4 register tile, direct coalesced
// h write, fused bias+relu+score.
static __global__ __launch_bounds__(512) void k_sage_mm(
    const float* __restrict__ x, const int* __restrict__ offs, const int* __restrict__ cnt,
    const int* __restrict__ list, const float* __restrict__ wlT, const float* __restrict__ blv,
    const float* __restrict__ wrT, const float* __restrict__ pvec,
    const float* __restrict__ pnbuf, int pidx, float* __restrict__ h,
    float* __restrict__ score) {
  __shared__ float smem[4224];  // xT[64*33] + mT[64*33], stride-33 (broadcast reads)
  __shared__ float psh[64], bsh[64];
  __shared__ int lds_list[CAPE];
  float* xT = smem;
  float* mT = smem + 2112;
  int t = threadIdx.x;
  size_t nb = (size_t)((blockIdx.x & 7) * (gridDim.x >> 3) + (blockIdx.x >> 3));

  if (t < 64) {
    psh[t] = pvec[t];
    bsh[t] = blv[t];
  }
  int gv0 = (int)nb * 32;
  // stage x tile: 512 float4 = 1 per thread
  {
    const float4* x4 = (const float4*)(x + (size_t)gv0 * 64);
    int node = t >> 4, db = (t & 15) << 2;
    float4 a = x4[t];
    float av[4] = {a.x, a.y, a.z, a.w};
#pragma unroll
    for (int j = 0; j < 4; ++j) xT[(db + j) * 33 + node] = av[j];
  }
  int st0 = offs[gv0];
  int nedge = offs[gv0 + 31] + cnt[gv0 + 31] - st0;
  int ncap = (nedge < CAPE) ? nedge : CAPE;
  for (int e = t; e < ncap; e += 512) lds_list[e] = list[st0 + e];
  __syncthreads();

  // gather: wave w (of 8) handles nodes w*4..w*4+3, branchless 4 loads in flight
  {
    int lane = t & 63, w = t >> 6;
    int stq[4], cq[4];
    float accq[4];
    int cmax = 0;
#pragma unroll
    for (int q = 0; q < 4; ++q) {
      int gv = gv0 + w * 4 + q;
      stq[q] = offs[gv] - st0;
      cq[q] = cnt[gv];
      accq[q] = 0.f;
      cmax = max(cmax, cq[q]);
    }
    int ncl = (nedge > 0) ? (nedge - 1) : 0;
    for (int j = 0; j < cmax; ++j) {
#pragma unroll
      for (int q = 0; q < 4; ++q) {
        bool act = j < cq[q];
        int idx = stq[q] + (act ? j : 0);
        idx = (idx < ncl) ? idx : ncl;
        int sn = (idx < ncap) ? lds_list[idx] : list[st0 + idx];
        float xv = x[(size_t)(sn & 32767) * 64 + lane];
        accq[q] = act ? (accq[q] + xv) : accq[q];
      }
    }
#pragma unroll
    for (int q = 0; q < 4; ++q) {
      int node = w * 4 + q;
      mT[lane * 33 + node] = accq[q] * (1.0f / fmaxf((float)cq[q], 1.0f));
    }
  }
  __syncthreads();

  int tx = t & 15, row = t >> 4;  // tx: col group (4 cols), row in [0,32)
  float acc[4] = {};
#pragma unroll 4
  for (int k = 0; k < 64; ++k) {
    int cb = ((tx ^ (k & 15)) << 2);
    float a = xT[k * 33 + row];
    float m = mT[k * 33 + row];
    const float4 L = *(const float4*)&wlT[(k << 6) + cb];
    const float4 R = *(const float4*)&wrT[(k << 6) + cb];
    float Lv[4] = {L.x, L.y, L.z, L.w}, Rv[4] = {R.x, R.y, R.z, R.w};
#pragma unroll
    for (int c = 0; c < 4; ++c) acc[c] += m * Lv[c] + a * Rv[c];
  }

  float pn = pnbuf[pidx];
  float hv[4];
  double sp = 0.0;
#pragma unroll
  for (int c = 0; c < 4; ++c) {
    float v = fmaxf(acc[c] + bsh[(tx << 2) + c], 0.0f);
    hv[c] = v;
    sp += (double)v * (double)psh[(tx << 2) + c];
  }
  // direct coalesced h write
  {
    float4 o4 = {hv[0], hv[1], hv[2], hv[3]};
    *(float4*)&h[(size_t)(gv0 + row) * 64 + (tx << 2)] = o4;
  }
  __syncthreads();  // reuse smem for score reduction
  double* sred = (double*)smem;  // [16][32]
  sred[(tx << 5) + row] = sp;
  __syncthreads();
  if (t < 32) {
    double ssum = 0.0;
#pragma unroll
    for (int g = 0; g < 16; ++g) ssum += sred[(g << 5) + t];
    score[gv0 + t] = (float)ssum * pn;
  }
}

// ---------------- GCN ----------------

static __global__ __launch_bounds__(256) void k_gcn_mm(const float* __restrict__ x,
                                                       const float* __restrict__ wT,
                                                       float* __restrict__ h1) {
  __shared__ float smem[4608];
  float* xT = smem;
  int t = threadIdx.x;
  size_t nb = blockIdx.x;
  const float4* x4 = (const float4*)(x + nb * 4096);
  for (int i = t; i < 1024; i += 256) {
    int node = i >> 4, db = (i & 15) << 2;
    float4 a = x4[i];
    float av[4] = {a.x, a.y, a.z, a.w};
    int ng = node >> 2, n0 = node & 3;
#pragma unroll
    for (int j = 0; j < 4; ++j) {
      int d = db + j;
      xT[(d << 6) + (((ng ^ (d & 15)) << 2) | n0)] = av[j];
    }
  }
  __syncthreads();
  int tx = t & 15, ty = t >> 4;
  float acc[4][4] = {};
#pragma unroll 4
  for (int k = 0; k < 64; ++k) {
    int s = k & 15;
    const float4 a = *(const float4*)&xT[(k << 6) + ((tx ^ s) << 2)];
    const float4 W = *(const float4*)&wT[(k << 6) + ((ty ^ s) << 2)];
    float A[4] = {a.x, a.y, a.z, a.w}, Wv[4] = {W.x, W.y, W.z, W.w};
#pragma unroll
    for (int r = 0; r < 4; ++r)
#pragma unroll
      for (int c = 0; c < 4; ++c) acc[r][c] += A[r] * Wv[c];
  }
  __syncthreads();
  float* hT = smem;
#pragma unroll
  for (int r = 0; r < 4; ++r) {
    int node = (tx << 2) + r;
    int nk = node & 15;
#pragma unroll
    for (int c = 0; c < 4; ++c) hT[node * 68 + (((ty ^ nk) << 2) | c)] = acc[r][c];
  }
  __syncthreads();
  float4* h4 = (float4*)(h1 + nb * 4096);
  for (int i = t; i < 1024; i += 256) {
    int node = i >> 4, q = i & 15;
    h4[i] = *(const float4*)&hT[node * 68 + ((q ^ (node & 15)) << 2)];
  }
}

// sentinel-CSR gather: iterate slice (len entries, -1 skipped), vcnt = valid counts
static __global__ void k_gcn_gather(const float* __restrict__ h1, const int* __restrict__ offs,
                                    const int* __restrict__ lenarr, const int* __restrict__ vcnt,
                                    const int* __restrict__ list, const float* __restrict__ b,
                                    const float* __restrict__ pvec,
                                    const float* __restrict__ pnbuf, int pidx,
                                    float* __restrict__ h, float* __restrict__ score, int ntot) {
  int lane = threadIdx.x & 63, vl = threadIdx.x >> 6;
  int v = blockIdx.x * 4 + vl;
  if (v >= ntot) return;
  int st = offs[v], len = lenarr[v];
  float degv = 1.0f + (float)vcnt[v];
  float ivd = 1.0f / sqrtf(degv);
  float acc = 0.f;
  for (int j = 0; j < len; ++j) {
    int e = list[st + j];
    if (e >= 0) {
      float nrm = (1.0f / sqrtf(1.0f + (float)vcnt[e])) * ivd;
      acc += h1[(size_t)e * 64 + lane] * nrm;
    }
  }
  float outv = fmaxf(acc + h1[(size_t)v * 64 + lane] * (1.0f / degv) + b[lane], 0.0f);
  h[(size_t)v * 64 + lane] = outv;
  double sc = (double)outv * (double)pvec[lane];
#pragma unroll
  for (int off = 1; off < 64; off <<= 1) sc += __shfl_xor(sc, off);
  if (lane == 0) score[v] = (float)sc * pnbuf[pidx];
}

// ---------------- TopK pool: chunk bitonic (<=1024) + merge-path ----------------

static __global__ void k_chunksort(const float* __restrict__ score,
                                   unsigned long long* __restrict__ runs, int n_per, int k,
                                   int* __restrict__ newidx, int* __restrict__ perm, int single) {
  extern __shared__ unsigned long long sk[];
  int CH = blockDim.x;
  int g0 = blockIdx.x * CH;
  int b = g0 / n_per;
  int i = threadIdx.x;
  int gi = g0 + i;
  int li = gi - b * n_per;
  unsigned u = __float_as_uint(score[gi]);
  unsigned s = (u & 0x80000000u) ? u : ~(u | 0x80000000u);
  sk[i] = ((unsigned long long)s << 32) | (unsigned)li;
  __syncthreads();
  for (int ksz = 2; ksz <= CH; ksz <<= 1) {
    for (int j = ksz >> 1; j > 0; j >>= 1) {
      int ixj = i ^ j;
      if (ixj > i) {
        unsigned long long a = sk[i], c = sk[ixj];
        bool up = ((i & ksz) == 0);
        if ((a > c) == up) {
          sk[i] = c;
          sk[ixj] = a;
        }
      }
      __syncthreads();
    }
  }
  if (!single) {
    runs[gi] = sk[i];
  } else {
    int r = i;
    int idx = (int)(sk[r] & 0xFFFFFFFFu);
    int gidx = b * n_per + idx;
    if (r < k) {
      perm[b * k + r] = gidx;
      newidx[gidx] = b * k + r;
    } else {
      newidx[gidx] = -1;
    }
  }
}

static __global__ void k_merge(const unsigned long long* __restrict__ in,
                               unsigned long long* __restrict__ out, int L, int ntot, int n_per,
                               int k, int* __restrict__ newidx, int* __restrict__ perm,
                               int final) {
  int g = blockIdx.x * 256 + threadIdx.x;
  if (g >= ntot) return;
  unsigned long long key = in[g];
  int pair = g / (2 * L);
  int base = pair * 2 * L;
  int t = g - base;
  const unsigned long long* sib;
  int p;
  if (t < L) {
    sib = in + base + L;
    p = t;
  } else {
    sib = in + base;
    p = t - L;
  }
  int lo = 0, hi = L;
  while (lo < hi) {
    int mid = (lo + hi) >> 1;
    lo = (sib[mid] < key) ? mid + 1 : lo;
    hi = (sib[mid] < key) ? hi : mid;
  }
  int pos = p + lo;
  if (!final) {
    out[base + pos] = key;
  } else {
    int b = base / n_per;
    int idx = (int)(key & 0xFFFFFFFFu);
    int gidx = b * n_per + idx;
    if (pos < k) {
      perm[b * k + pos] = gidx;
      newidx[gidx] = b * k + pos;
    } else {
      newidx[gidx] = -1;
    }
  }
}

// ---------------- pool_post: gather_ro | vcnt-count | flat remap ----------------

static __global__ __launch_bounds__(1024) void k_pool_post(
    const float* __restrict__ h, const float* __restrict__ score, const int* __restrict__ perm,
    float* __restrict__ xnew, float* __restrict__ pmax, float* __restrict__ psum, int base,
    const int* __restrict__ offs, const int* __restrict__ lenarr, const int* __restrict__ list,
    const int* __restrict__ newidx, int* __restrict__ ncnt, int* __restrict__ noffs,
    int* __restrict__ nlen, int newn, int G1, int G2, const int* __restrict__ rin,
    int* __restrict__ rout, int rn) {
  __shared__ float tile[64 * 68];
  __shared__ float pm[16][65], ps[16][65];
  int t = threadIdx.x;
  int bid = blockIdx.x;
  if (bid >= G1 + G2) {
    int e = (bid - G1 - G2) * 1024 + t;
    if (e < rn) {
      int v = rin[e];
      rout[e] = (v >= 0 && v < 65536) ? newidx[v] : -1;
    }
    return;
  }
  if (bid >= G1) {
    int nn = (bid - G1) * 1024 + t;
    if (nn >= newn) return;
    int old = perm[nn];
    int st = offs[old], c = lenarr[old];
    int cc = 0;
    for (int j = 0; j < c; ++j) {
      int e = list[st + j];
      cc += (e >= 0 && newidx[e] >= 0);
    }
    ncnt[nn] = cc;
    return;
  }
  int node = t >> 4, q = t & 15;
  int nn = bid * 64 + node;
  int old = perm[nn];
  if (noffs && t < 64) {
    int nn2 = bid * 64 + t;
    int o2 = perm[nn2];
    noffs[nn2] = offs[o2];
    nlen[nn2] = lenarr[o2];
  }
  float tm = tanhf(score[old]);
  float4 v = *(const float4*)&h[(size_t)old * 64 + q * 4];
  v.x *= tm;
  v.y *= tm;
  v.z *= tm;
  v.w *= tm;
  *(float4*)&xnew[(size_t)nn * 64 + q * 4] = v;
  *(float4*)&tile[node * 68 + ((q ^ (node & 15)) << 2)] = v;
  __syncthreads();
  int slot = t >> 6, d = t & 63;
  int q2 = d >> 2, i3 = d & 3;
  float m = -INFINITY, s = 0.f;
#pragma unroll
  for (int r = 0; r < 4; ++r) {
    int nd = slot * 4 + r;
    float val = tile[nd * 68 + (((q2 ^ (nd & 15)) << 2) | i3)];
    m = fmaxf(m, val);
    s += val;
  }
  pm[slot][d] = m;
  ps[slot][d] = s;
  __syncthreads();
  if (t < 64) {
    float mm = -INFINITY, ss = 0.f;
#pragma unroll
    for (int sl = 0; sl < 16; ++sl) {
      mm = fmaxf(mm, pm[sl][t]);
      ss += ps[sl][t];
    }
    pmax[(size_t)(base + bid) * 64 + t] = mm;
    psum[(size_t)(base + bid) * 64 + t] = ss;
  }
}

// ---------------- MLP + softmax (with deferred readout combine) ----------------

static __global__ void k_mlp(const float* __restrict__ pmax, const float* __restrict__ psum,
                             const float* __restrict__ lw1, const float* __restrict__ lb1,
                             const float* __restrict__ lw2, const float* __restrict__ lb2,
                             const float* __restrict__ lw3, const float* __restrict__ lb3,
                             float* __restrict__ out) {
  __shared__ float zs[128], t1[128], t2[64], t3[256], red[256];
  int b = blockIdx.x, tid = threadIdx.x;
  const int baseL[6] = {0, 512, 768, 896, 960, 992};
  const int nchL[6] = {32, 16, 8, 4, 2, 1};
  const int kkL[6] = {2048, 1024, 512, 256, 128, 64};
  if (tid < 64) {
    float zm = 0.f;
    for (int i = 0; i < 6; ++i) {
      float m = -INFINITY;
      for (int c = 0; c < nchL[i]; ++c)
        m = fmaxf(m, pmax[(size_t)(baseL[i] + b * nchL[i] + c) * 64 + tid]);
      zm += m;
    }
    zs[tid] = zm;
  } else if (tid < 128) {
    int d = tid - 64;
    float zsum = 0.f;
    for (int i = 0; i < 6; ++i) {
      float s = 0.f;
      for (int c = 0; c < nchL[i]; ++c)
        s += psum[(size_t)(baseL[i] + b * nchL[i] + c) * 64 + d];
      zsum += s / (float)kkL[i];
    }
    zs[tid] = zsum;
  }
  __syncthreads();
  if (tid < 128) {
    double a = 0.0;
    for (int d = 0; d < 128; ++d) a += (double)lw1[tid * 128 + d] * (double)zs[d];
    t1[tid] = fmaxf((float)a + lb1[tid], 0.0f);
  }
  __syncthreads();
  if (tid < 64) {
    double a = 0.0;
    for (int d = 0; d < 128; ++d) a += (double)lw2[tid * 128 + d] * (double)t1[d];
    t2[tid] = fmaxf((float)a + lb2[tid], 0.0f);
  }
  __syncthreads();
  {
    double a = 0.0;
    for (int d = 0; d < 64; ++d) a += (double)lw3[tid * 64 + d] * (double)t2[d];
    t3[tid] = (float)a + lb3[tid];
  }
  __syncthreads();
  red[tid] = t3[tid];
  __syncthreads();
  for (int s = 128; s > 0; s >>= 1) {
    if (tid < s) red[tid] = fmaxf(red[tid], red[tid + s]);
    __syncthreads();
  }
  float mx = red[0];
  __syncthreads();
  float e = expf(t3[tid] - mx);
  red[tid] = e;
  __syncthreads();
  for (int s = 128; s > 0; s >>= 1) {
    if (tid < s) red[tid] += red[tid + s];
    __syncthreads();
  }
  out[b * 256 + tid] = e / red[0];
}

// ---------------- launch ----------------

extern "C" void kernel_launch(void* const* d_in, const int* in_sizes, int n_in,
                              void* d_out, int out_size, void* d_ws, size_t ws_size,
                              hipStream_t stream) {
  const float* x0 = (const float*)d_in[0];
  const int* esrc0 = (const int*)d_in[1];
  const int* edst0 = (const int*)d_in[2];
  const float* WL[3] = {(const float*)d_in[3], (const float*)d_in[6], (const float*)d_in[9]};
  const float* BL[3] = {(const float*)d_in[4], (const float*)d_in[7], (const float*)d_in[10]};
  const float* WR[3] = {(const float*)d_in[5], (const float*)d_in[8], (const float*)d_in[11]};
  const float* WG[3] = {(const float*)d_in[12], (const float*)d_in[14], (const float*)d_in[16]};
  const float* BG[3] = {(const float*)d_in[13], (const float*)d_in[15], (const float*)d_in[17]};
  const float* P[6] = {(const float*)d_in[18], (const float*)d_in[19], (const float*)d_in[20],
                       (const float*)d_in[21], (const float*)d_in[22], (const float*)d_in[23]};
  const float* lw1 = (const float*)d_in[24];
  const float* lb1 = (const float*)d_in[25];
  const float* lw2 = (const float*)d_in[26];
  const float* lb2 = (const float*)d_in[27];
  const float* lw3 = (const float*)d_in[28];
  const float* lb3 = (const float*)d_in[29];

  char* ws = (char*)d_ws;
  size_t off = 0;
  auto alloc = [&](size_t bytes) -> void* {
    void* p = ws + off;
    off += (bytes + 255) & ~(size_t)255;
    return p;
  };
  float* hA = (float*)alloc((size_t)65536 * 64 * 4);
  float* hB = (float*)alloc((size_t)32768 * 64 * 4);
  float* tmp = (float*)alloc((size_t)8192 * 64 * 4);
  float* score = (float*)alloc((size_t)65536 * 4);
  int* newidx = (int*)alloc((size_t)65536 * 4);
  int* perm = (int*)alloc((size_t)32768 * 4);
  int* cntA = (int*)alloc((size_t)65536 * 4);
  int* cntB = (int*)alloc((size_t)65536 * 4);
  int* offsA = (int*)alloc((size_t)65536 * 4);
  int* offsB = (int*)alloc((size_t)65536 * 4);
  int* lenA = (int*)alloc((size_t)32768 * 4);
  int* lenB = (int*)alloc((size_t)32768 * 4);
  int* cursor = (int*)alloc((size_t)65536 * 4);
  int* bsum = (int*)alloc((size_t)64 * 4);
  int* listA = (int*)alloc((size_t)NE * 4);
  int* listB = (int*)alloc((size_t)NE * 4);
  float* pmax = (float*)alloc((size_t)1024 * 64 * 4);
  float* psum = (float*)alloc((size_t)1024 * 64 * 4);
  unsigned long long* keyA = (unsigned long long*)alloc((size_t)65536 * 8);
  unsigned long long* keyB = (unsigned long long*)alloc((size_t)65536 * 8);
  float* pnbuf = (float*)alloc((size_t)64 * 4);
  float* wp = (float*)alloc((size_t)7 * 4096 * 4);
  if (off > ws_size) return;  // workspace too small — bail

  auto scan = [&](int* cntp, int* offsp, int* curp, int n) {
    int nblk = (n + 1023) / 1024;
    k_scan1<<<nblk, 256, 0, stream>>>(cntp, offsp, bsum, n);
    k_scan3<<<(n + 255) / 256, 256, 0, stream>>>(offsp, curp, bsum, n, nblk);
  };

  k_pw<<<13, 256, 0, stream>>>(P[0], P[1], P[2], P[3], P[4], P[5], WL[1], WR[1], WL[2], WR[2],
                               WG[0], WG[1], WG[2], pnbuf, wp);

  // build layer-0 CSR (dst-sorted src lists)
  hipMemsetAsync(cntA, 0, (size_t)65536 * 4, stream);
  k_count<<<NE / 256, 256, 0, stream>>>(edst0, cntA);
  scan(cntA, offsA, cursor, 65536);
  k_fill0<<<NE / 256, 256, 0, stream>>>(esrc0, edst0, cursor, listA);

  const float* xcur = x0;
  int* ccnt = cntA;
  int* coffs = offsA;
  int* clist = listA;
  int* clen = nullptr;
  const int baseL[6] = {0, 512, 768, 896, 960, 992};

  for (int i = 0; i < 6; ++i) {
    int n_per = N0 >> i;
    int ntot = NB * n_per;
    int k = n_per >> 1;

    if (i == 0) {
      k_sage0<<<ntot / 64, 1024, 0, stream>>>(xcur, coffs, ccnt, clist, WL[0], BL[0], WR[0],
                                              P[0], pnbuf, hA, score);
    } else if (i < 3) {
      const float* wlp = wp + (size_t)((i - 1) * 2 + 0) * 4096;
      const float* wrp = wp + (size_t)((i - 1) * 2 + 1) * 4096;
      k_sage_mm<<<ntot / 32, 512, 0, stream>>>(xcur, coffs, ccnt, clist, wlp, BL[i], wrp, P[i],
                                               pnbuf, i, hA, score);
    } else {
      int g = i - 3;
      k_gcn_mm<<<ntot / 64, 256, 0, stream>>>(xcur, wp + (size_t)(4 + g) * 4096, tmp);
      k_gcn_gather<<<(ntot + 3) / 4, 256, 0, stream>>>(tmp, coffs, clen ? clen : ccnt, ccnt,
                                                       clist, BG[g], P[i], pnbuf, i, hA, score,
                                                       ntot);
    }

    // pool i: chunk sort (<=1024) + merge-path rounds
    int CH = (n_per < 1024) ? n_per : 1024;
    int single = (CH == n_per) ? 1 : 0;
    k_chunksort<<<ntot / CH, CH, (size_t)CH * 8, stream>>>(score, keyA, n_per, k, newidx, perm,
                                                           single);
    if (!single) {
      unsigned long long* cur = keyA;
      unsigned long long* nxt = keyB;
      for (int L = CH; L * 2 <= n_per; L <<= 1) {
        int fin = (L * 2 == n_per) ? 1 : 0;
        k_merge<<<(ntot + 255) / 256, 256, 0, stream>>>(cur, nxt, L, ntot, n_per, k, newidx, perm,
                                                        fin);
        unsigned long long* t2 = cur;
        cur = nxt;
        nxt = t2;
      }
    }

    int nch = k / 64;
    int G1 = NB * nch;
    int newn = (i < 5) ? NB * k : 0;
    int compacted_out = (i < 2);
    int sentinel_out = (i >= 2 && i < 5);
    int* ncnt = (i & 1) ? cntA : cntB;
    int* noffs = (i & 1) ? offsA : offsB;
    int* nlen = (i & 1) ? lenA : lenB;
    int* nlist = (i & 1) ? listA : listB;
    int G2 = (newn > 0) ? (newn + 1023) / 1024 : 0;
    int G3 = sentinel_out ? (NE / 1024) : 0;
    const int* lenarr = clen ? clen : ccnt;
    k_pool_post<<<G1 + G2 + G3, 1024, 0, stream>>>(
        hA, score, perm, hB, pmax, psum, baseL[i], coffs, lenarr, clist, newidx, ncnt,
        sentinel_out ? noffs : nullptr, sentinel_out ? nlen : nullptr, newn, G1, G2, clist,
        nlist, G3 ? NE : 0);

    if (compacted_out) {
      scan(ncnt, noffs, nullptr, newn);
      k_newfill<<<(newn + 255) / 256, 256, 0, stream>>>(perm, coffs, ccnt, clist, newidx, noffs,
                                                        nlist, newn);
      ccnt = ncnt;
      coffs = noffs;
      clist = nlist;
      clen = nullptr;
    } else if (sentinel_out) {
      ccnt = ncnt;
      coffs = noffs;
      clist = nlist;
      clen = nlen;
    }

    xcur = hB;
  }

  k_mlp<<<NB, 256, 0, stream>>>(pmax, psum, lw1, lb1, lw2, lb2, lw3, lb3, (float*)d_out);
}

// Round 16
// 339.942 us; speedup vs baseline: 1.0337x; 1.0337x over previous
//
#include <hip/hip_runtime.h>
#include <math.h>

#define NB 16
#define N0 4096
#define NE 524288
#define CAPE 1280

// ---------------- CSR build (layer 0, atomic int cursor only) ----------------

static __global__ void k_count(const int* __restrict__ dst, int* __restrict__ cnt) {
  int e = blockIdx.x * 256 + threadIdx.x;
  if (e >= NE) return;
  atomicAdd(&cnt[dst[e]], 1);
}

static __global__ void k_fill0(const int* __restrict__ src, const int* __restrict__ dst,
                               int* __restrict__ cursor, int* __restrict__ list) {
  int e = blockIdx.x * 256 + threadIdx.x;
  if (e >= NE) return;
  int d = dst[e];
  int slot = atomicAdd(&cursor[d], 1);
  list[slot] = src[e];
}

// ---------------- exclusive scan (scan1 + scan3-with-inline-bsum-prefix) ----------------

static __global__ void k_scan1(const int* __restrict__ in, int* __restrict__ out,
                               int* __restrict__ bsum, int n) {
  __shared__ int ts[256];
  int base = blockIdx.x * 1024 + threadIdx.x * 4;
  int a0 = (base + 0 < n) ? in[base + 0] : 0;
  int a1 = (base + 1 < n) ? in[base + 1] : 0;
  int a2 = (base + 2 < n) ? in[base + 2] : 0;
  int a3 = (base + 3 < n) ? in[base + 3] : 0;
  int s = a0 + a1 + a2 + a3;
  ts[threadIdx.x] = s;
  __syncthreads();
  for (int off = 1; off < 256; off <<= 1) {
    int v = (threadIdx.x >= off) ? ts[threadIdx.x - off] : 0;
    __syncthreads();
    ts[threadIdx.x] += v;
    __syncthreads();
  }
  int excl = ts[threadIdx.x] - s;
  if (base + 0 < n) out[base + 0] = excl;
  excl += a0;
  if (base + 1 < n) out[base + 1] = excl;
  excl += a1;
  if (base + 2 < n) out[base + 2] = excl;
  excl += a2;
  if (base + 3 < n) out[base + 3] = excl;
  if (threadIdx.x == 255) bsum[blockIdx.x] = ts[255];
}

static __global__ void k_scan3(int* __restrict__ out, int* __restrict__ out2,
                               const int* __restrict__ bsum, int n, int nblk) {
  __shared__ int sb[64];
  int t = threadIdx.x;
  if (t < 64) {
    int v = (t < nblk) ? bsum[t] : 0;
    int p = v;
    for (int off = 1; off < 64; off <<= 1) {
      int u = __shfl_up(p, off);
      if (t >= off) p += u;
    }
    sb[t] = p - v;
  }
  __syncthreads();
  int i = blockIdx.x * 256 + t;
  if (i < n) {
    int v = out[i] + sb[i >> 10];
    out[i] = v;
    if (out2) out2[i] = v;
  }
}

// ---------------- CSR compaction fill (pools 0,1 only) ----------------

static __global__ void k_newfill(const int* __restrict__ perm, const int* __restrict__ offs,
                                 const int* __restrict__ cnt, const int* __restrict__ list,
                                 const int* __restrict__ newidx, const int* __restrict__ noffs,
                                 int* __restrict__ nlist, int newn) {
  int nn = blockIdx.x * 256 + threadIdx.x;
  if (nn >= newn) return;
  int old = perm[nn];
  int st = offs[old], c = cnt[old];
  int pos = noffs[nn];
  for (int j = 0; j < c; ++j) {
    int s2 = newidx[list[st + j]];
    if (s2 >= 0) nlist[pos++] = s2;
  }
}

// ---------------- fused pnorm (blocks 0-5) + weight prep (blocks 6-12) ----------------

static __global__ void k_pw(const float* __restrict__ p0, const float* __restrict__ p1,
                            const float* __restrict__ p2, const float* __restrict__ p3,
                            const float* __restrict__ p4, const float* __restrict__ p5,
                            const float* __restrict__ w0, const float* __restrict__ w1,
                            const float* __restrict__ w2, const float* __restrict__ w3,
                            const float* __restrict__ w4, const float* __restrict__ w5,
                            const float* __restrict__ w6, float* __restrict__ pnbuf,
                            float* __restrict__ wp) {
  if (blockIdx.x < 6) {
    if (threadIdx.x >= 64) return;
    const float* pp = p0;
    switch (blockIdx.x) {
      case 1: pp = p1; break;
      case 2: pp = p2; break;
      case 3: pp = p3; break;
      case 4: pp = p4; break;
      case 5: pp = p5; break;
      default: break;
    }
    double v = (double)pp[threadIdx.x];
    v *= v;
#pragma unroll
    for (int off = 1; off < 64; off <<= 1) v += __shfl_xor(v, off);
    if (threadIdx.x == 0) pnbuf[blockIdx.x] = (float)(1.0 / sqrt(v));
  } else {
    int wi = blockIdx.x - 6;
    const float* src = w0;
    switch (wi) {
      case 1: src = w1; break;
      case 2: src = w2; break;
      case 3: src = w3; break;
      case 4: src = w4; break;
      case 5: src = w5; break;
      case 6: src = w6; break;
      default: break;
    }
    float* dst = wp + (size_t)wi * 4096;
    const float4* w4p = (const float4*)src;
    for (int i4 = threadIdx.x; i4 < 1024; i4 += 256) {
      int o = i4 >> 4, db = (i4 & 15) << 2;
      float4 W = w4p[i4];
      float Wv[4] = {W.x, W.y, W.z, W.w};
      int og = o >> 2, o3 = o & 3;
#pragma unroll
      for (int j = 0; j < 4; ++j) {
        int d = db + j;
        dst[(d << 6) + (((og ^ (d & 15)) << 2) | o3)] = Wv[j];
      }
    }
  }
}

// ---------------- SAGE layer 0 (DIN=2): fused mean (64 nodes/block, 1 thread/node)
// + linear + relu + score. 1024 threads: phase1 t<64 one node each; phase2 16 waves x 4 nodes.

static __global__ __launch_bounds__(1024) void k_sage0(
    const float* __restrict__ x, const int* __restrict__ offs, const int* __restrict__ cnt,
    const int* __restrict__ list, const float* __restrict__ wl, const float* __restrict__ blv,
    const float* __restrict__ wr, const float* __restrict__ pvec,
    const float* __restrict__ pnbuf, float* __restrict__ h, float* __restrict__ score) {
  __shared__ float wlT[2][65], wrT[2][65];
  __shared__ float msh[64][2];
  int t = threadIdx.x;
  if (t < 128) {
    int o = t >> 1, d = t & 1;
    wlT[d][o] = wl[o * 2 + d];
    wrT[d][o] = wr[o * 2 + d];
  }
  if (t < 64) {
    int v = blockIdx.x * 64 + t;
    int st = offs[v], c = cnt[v];
    float s0 = 0.f, s1 = 0.f;
    for (int j = 0; j < c; ++j) {
      int s = list[st + j];
      s0 += x[s * 2 + 0];
      s1 += x[s * 2 + 1];
    }
    float inv = 1.0f / fmaxf((float)c, 1.0f);
    msh[t][0] = s0 * inv;
    msh[t][1] = s1 * inv;
  }
  __syncthreads();
  int o = t & 63, w = t >> 6;  // 16 waves
  float pn = pnbuf[0];
  float psl = pvec[o];
#pragma unroll
  for (int r = 0; r < 4; ++r) {
    int node = w * 4 + r;
    int v = blockIdx.x * 64 + node;
    float acc = blv[o] + msh[node][0] * wlT[0][o] + msh[node][1] * wlT[1][o] +
                x[v * 2 + 0] * wrT[0][o] + x[v * 2 + 1] * wrT[1][o];
    float hval = fmaxf(acc, 0.0f);
    h[(size_t)v * 64 + o] = hval;
    double sc = (double)hval * (double)psl;
#pragma unroll
    for (int off = 1; off < 64; off <<= 1) sc += __shfl_xor(sc, off);
    if (o == 0) score[v] = (float)sc * pn;
  }
}

// Fused SAGE DIN=64, 512 threads (8 waves), 64-node tile: XCD swizzle, LDS list
// staging, branchless 8-way ILP gather, 2x4 register-tile GEMM, bias+relu+score.
static __global__ __launch_bounds__(512) void k_sage_mm(
    const float* __restrict__ x, const int* __restrict__ offs, const int* __restrict__ cnt,
    const int* __restrict__ list, const float* __restrict__ wlT, const float* __restrict__ blv,
    const float* __restrict__ wrT, const float* __restrict__ pvec,
    const float* __restrict__ pnbuf, int pidx, float* __restrict__ h,
    float* __restrict__ score) {
  __shared__ float smem[8192];
  __shared__ float psh[64], bsh[64];
  __shared__ int lds_list[CAPE];
  float* xT = smem;
  float* mT = smem + 4096;
  int t = threadIdx.x;
  size_t nb = (size_t)((blockIdx.x & 7) * (gridDim.x >> 3) + (blockIdx.x >> 3));

  if (t < 64) {
    psh[t] = pvec[t];
    bsh[t] = blv[t];
  }
  const float4* x4 = (const float4*)(x + nb * 4096);
  for (int i = t; i < 1024; i += 512) {
    int node = i >> 4, db = (i & 15) << 2;
    float4 a = x4[i];
    float av[4] = {a.x, a.y, a.z, a.w};
    int ng = node >> 2, n0 = node & 3;
#pragma unroll
    for (int j = 0; j < 4; ++j) {
      int d = db + j;
      xT[(d << 6) + (((ng ^ (d & 15)) << 2) | n0)] = av[j];
    }
  }
  int gv0 = (int)nb * 64;
  int st0 = offs[gv0];
  int nedge = offs[gv0 + 63] + cnt[gv0 + 63] - st0;
  int ncap = (nedge < CAPE) ? nedge : CAPE;
  for (int e = t; e < ncap; e += 512) lds_list[e] = list[st0 + e];
  __syncthreads();

  {
    int lane = t & 63, w = t >> 6;
    int stq[8], cq[8];
    float accq[8];
    int cmax = 0;
#pragma unroll
    for (int q = 0; q < 8; ++q) {
      int gv = gv0 + w * 8 + q;
      stq[q] = offs[gv] - st0;
      cq[q] = cnt[gv];
      accq[q] = 0.f;
      cmax = max(cmax, cq[q]);
    }
    int ncl = (nedge > 0) ? (nedge - 1) : 0;
    for (int j = 0; j < cmax; ++j) {
#pragma unroll
      for (int q = 0; q < 8; ++q) {
        bool act = j < cq[q];
        int idx = stq[q] + (act ? j : 0);
        idx = (idx < ncl) ? idx : ncl;
        int sn = (idx < ncap) ? lds_list[idx] : list[st0 + idx];
        float xv = x[(size_t)(sn & 32767) * 64 + lane];
        accq[q] = act ? (accq[q] + xv) : accq[q];
      }
    }
#pragma unroll
    for (int q = 0; q < 8; ++q) {
      int node = w * 8 + q;
      float mval = accq[q] * (1.0f / fmaxf((float)cq[q], 1.0f));
      int col = (((node >> 2) ^ (lane & 15)) << 2) | (node & 3);
      mT[(lane << 6) + col] = mval;
    }
  }
  __syncthreads();

  int tx = t & 15, ty = t >> 4;
  int ng = ty >> 1, n0 = (ty & 1) << 1;
  float acc[2][4] = {};
#pragma unroll 4
  for (int k = 0; k < 64; ++k) {
    int s = k & 15;
    int ca = (((ng ^ s) << 2) | n0);
    const float2 a2 = *(const float2*)&xT[(k << 6) + ca];
    const float2 m2 = *(const float2*)&mT[(k << 6) + ca];
    const float4 L = *(const float4*)&wlT[(k << 6) + ((tx ^ s) << 2)];
    const float4 R = *(const float4*)&wrT[(k << 6) + ((tx ^ s) << 2)];
    float A[2] = {a2.x, a2.y}, M[2] = {m2.x, m2.y};
    float Lv[4] = {L.x, L.y, L.z, L.w}, Rv[4] = {R.x, R.y, R.z, R.w};
#pragma unroll
    for (int r = 0; r < 2; ++r)
#pragma unroll
      for (int c = 0; c < 4; ++c) acc[r][c] += M[r] * Lv[c] + A[r] * Rv[c];
  }

  float pn = pnbuf[pidx];
  float hv[2][4];
  double sp[2];
#pragma unroll
  for (int r = 0; r < 2; ++r) {
    sp[r] = 0.0;
#pragma unroll
    for (int c = 0; c < 4; ++c) {
      float v = fmaxf(acc[r][c] + bsh[(tx << 2) + c], 0.0f);
      hv[r][c] = v;
      sp[r] += (double)v * (double)psh[(tx << 2) + c];
    }
  }
  __syncthreads();
  float* hT = smem;
  double* sred = (double*)(smem + 4608);
#pragma unroll
  for (int r = 0; r < 2; ++r) {
    int node = (ty << 1) + r;
    int nk = node & 15;
#pragma unroll
    for (int c = 0; c < 4; ++c) hT[node * 68 + (((tx ^ nk) << 2) | c)] = hv[r][c];
    sred[(tx << 6) + node] = sp[r];
  }
  __syncthreads();
  float4* h4 = (float4*)(h + nb * 4096);
  for (int i = t; i < 1024; i += 512) {
    int node = i >> 4, q = i & 15;
    h4[i] = *(const float4*)&hT[node * 68 + ((q ^ (node & 15)) << 2)];
  }
  if (t < 64) {
    double ssum = 0.0;
    for (int g = 0; g < 16; ++g) ssum += sred[(g << 6) + t];
    score[nb * 64 + t] = (float)ssum * pn;
  }
}

// ---------------- GCN ----------------

static __global__ __launch_bounds__(256) void k_gcn_mm(const float* __restrict__ x,
                                                       const float* __restrict__ wT,
                                                       float* __restrict__ h1) {
  __shared__ float smem[4608];
  float* xT = smem;
  int t = threadIdx.x;
  size_t nb = blockIdx.x;
  const float4* x4 = (const float4*)(x + nb * 4096);
  for (int i = t; i < 1024; i += 256) {
    int node = i >> 4, db = (i & 15) << 2;
    float4 a = x4[i];
    float av[4] = {a.x, a.y, a.z, a.w};
    int ng = node >> 2, n0 = node & 3;
#pragma unroll
    for (int j = 0; j < 4; ++j) {
      int d = db + j;
      xT[(d << 6) + (((ng ^ (d & 15)) << 2) | n0)] = av[j];
    }
  }
  __syncthreads();
  int tx = t & 15, ty = t >> 4;
  float acc[4][4] = {};
#pragma unroll 4
  for (int k = 0; k < 64; ++k) {
    int s = k & 15;
    const float4 a = *(const float4*)&xT[(k << 6) + ((tx ^ s) << 2)];
    const float4 W = *(const float4*)&wT[(k << 6) + ((ty ^ s) << 2)];
    float A[4] = {a.x, a.y, a.z, a.w}, Wv[4] = {W.x, W.y, W.z, W.w};
#pragma unroll
    for (int r = 0; r < 4; ++r)
#pragma unroll
      for (int c = 0; c < 4; ++c) acc[r][c] += A[r] * Wv[c];
  }
  __syncthreads();
  float* hT = smem;
#pragma unroll
  for (int r = 0; r < 4; ++r) {
    int node = (tx << 2) + r;
    int nk = node & 15;
#pragma unroll
    for (int c = 0; c < 4; ++c) hT[node * 68 + (((ty ^ nk) << 2) | c)] = acc[r][c];
  }
  __syncthreads();
  float4* h4 = (float4*)(h1 + nb * 4096);
  for (int i = t; i < 1024; i += 256) {
    int node = i >> 4, q = i & 15;
    h4[i] = *(const float4*)&hT[node * 68 + ((q ^ (node & 15)) << 2)];
  }
}

// sentinel-CSR gather: iterate slice (len entries, -1 skipped), vcnt = valid counts
static __global__ void k_gcn_gather(const float* __restrict__ h1, const int* __restrict__ offs,
                                    const int* __restrict__ lenarr, const int* __restrict__ vcnt,
                                    const int* __restrict__ list, const float* __restrict__ b,
                                    const float* __restrict__ pvec,
                                    const float* __restrict__ pnbuf, int pidx,
                                    float* __restrict__ h, float* __restrict__ score, int ntot) {
  int lane = threadIdx.x & 63, vl = threadIdx.x >> 6;
  int v = blockIdx.x * 4 + vl;
  if (v >= ntot) return;
  int st = offs[v], len = lenarr[v];
  float degv = 1.0f + (float)vcnt[v];
  float ivd = 1.0f / sqrtf(degv);
  float acc = 0.f;
  for (int j = 0; j < len; ++j) {
    int e = list[st + j];
    if (e >= 0) {
      float nrm = (1.0f / sqrtf(1.0f + (float)vcnt[e])) * ivd;
      acc += h1[(size_t)e * 64 + lane] * nrm;
    }
  }
  float outv = fmaxf(acc + h1[(size_t)v * 64 + lane] * (1.0f / degv) + b[lane], 0.0f);
  h[(size_t)v * 64 + lane] = outv;
  double sc = (double)outv * (double)pvec[lane];
#pragma unroll
  for (int off = 1; off < 64; off <<= 1) sc += __shfl_xor(sc, off);
  if (lane == 0) score[v] = (float)sc * pnbuf[pidx];
}

// ---------------- TopK pool: chunk bitonic (<=1024) + merge-path ----------------

static __global__ void k_chunksort(const float* __restrict__ score,
                                   unsigned long long* __restrict__ runs, int n_per, int k,
                                   int* __restrict__ newidx, int* __restrict__ perm, int single) {
  extern __shared__ unsigned long long sk[];
  int CH = blockDim.x;
  int g0 = blockIdx.x * CH;
  int b = g0 / n_per;
  int i = threadIdx.x;
  int gi = g0 + i;
  int li = gi - b * n_per;
  unsigned u = __float_as_uint(score[gi]);
  unsigned s = (u & 0x80000000u) ? u : ~(u | 0x80000000u);
  sk[i] = ((unsigned long long)s << 32) | (unsigned)li;
  __syncthreads();
  for (int ksz = 2; ksz <= CH; ksz <<= 1) {
    for (int j = ksz >> 1; j > 0; j >>= 1) {
      int ixj = i ^ j;
      if (ixj > i) {
        unsigned long long a = sk[i], c = sk[ixj];
        bool up = ((i & ksz) == 0);
        if ((a > c) == up) {
          sk[i] = c;
          sk[ixj] = a;
        }
      }
      __syncthreads();
    }
  }
  if (!single) {
    runs[gi] = sk[i];
  } else {
    int r = i;
    int idx = (int)(sk[r] & 0xFFFFFFFFu);
    int gidx = b * n_per + idx;
    if (r < k) {
      perm[b * k + r] = gidx;
      newidx[gidx] = b * k + r;
    } else {
      newidx[gidx] = -1;
    }
  }
}

static __global__ void k_merge(const unsigned long long* __restrict__ in,
                               unsigned long long* __restrict__ out, int L, int ntot, int n_per,
                               int k, int* __restrict__ newidx, int* __restrict__ perm,
                               int final) {
  int g = blockIdx.x * 256 + threadIdx.x;
  if (g >= ntot) return;
  unsigned long long key = in[g];
  int pair = g / (2 * L);
  int base = pair * 2 * L;
  int t = g - base;
  const unsigned long long* sib;
  int p;
  if (t < L) {
    sib = in + base + L;
    p = t;
  } else {
    sib = in + base;
    p = t - L;
  }
  int lo = 0, hi = L;
  while (lo < hi) {
    int mid = (lo + hi) >> 1;
    lo = (sib[mid] < key) ? mid + 1 : lo;
    hi = (sib[mid] < key) ? hi : mid;
  }
  int pos = p + lo;
  if (!final) {
    out[base + pos] = key;
  } else {
    int b = base / n_per;
    int idx = (int)(key & 0xFFFFFFFFu);
    int gidx = b * n_per + idx;
    if (pos < k) {
      perm[b * k + pos] = gidx;
      newidx[gidx] = b * k + pos;
    } else {
      newidx[gidx] = -1;
    }
  }
}

// ---------------- pool_post: gather_ro | vcnt-count | flat remap ----------------

static __global__ __launch_bounds__(1024) void k_pool_post(
    const float* __restrict__ h, const float* __restrict__ score, const int* __restrict__ perm,
    float* __restrict__ xnew, float* __restrict__ pmax, float* __restrict__ psum, int base,
    const int* __restrict__ offs, const int* __restrict__ lenarr, const int* __restrict__ list,
    const int* __restrict__ newidx, int* __restrict__ ncnt, int* __restrict__ noffs,
    int* __restrict__ nlen, int newn, int G1, int G2, const int* __restrict__ rin,
    int* __restrict__ rout, int rn) {
  __shared__ float tile[64 * 68];
  __shared__ float pm[16][65], ps[16][65];
  int t = threadIdx.x;
  int bid = blockIdx.x;
  if (bid >= G1 + G2) {
    int e = (bid - G1 - G2) * 1024 + t;
    if (e < rn) {
      int v = rin[e];
      rout[e] = (v >= 0 && v < 65536) ? newidx[v] : -1;
    }
    return;
  }
  if (bid >= G1) {
    int nn = (bid - G1) * 1024 + t;
    if (nn >= newn) return;
    int old = perm[nn];
    int st = offs[old], c = lenarr[old];
    int cc = 0;
    for (int j = 0; j < c; ++j) {
      int e = list[st + j];
      cc += (e >= 0 && newidx[e] >= 0);
    }
    ncnt[nn] = cc;
    return;
  }
  int node = t >> 4, q = t & 15;
  int nn = bid * 64 + node;
  int old = perm[nn];
  if (noffs && t < 64) {
    int nn2 = bid * 64 + t;
    int o2 = perm[nn2];
    noffs[nn2] = offs[o2];
    nlen[nn2] = lenarr[o2];
  }
  float tm = tanhf(score[old]);
  float4 v = *(const float4*)&h[(size_t)old * 64 + q * 4];
  v.x *= tm;
  v.y *= tm;
  v.z *= tm;
  v.w *= tm;
  *(float4*)&xnew[(size_t)nn * 64 + q * 4] = v;
  *(float4*)&tile[node * 68 + ((q ^ (node & 15)) << 2)] = v;
  __syncthreads();
  int slot = t >> 6, d = t & 63;
  int q2 = d >> 2, i3 = d & 3;
  float m = -INFINITY, s = 0.f;
#pragma unroll
  for (int r = 0; r < 4; ++r) {
    int nd = slot * 4 + r;
    float val = tile[nd * 68 + (((q2 ^ (nd & 15)) << 2) | i3)];
    m = fmaxf(m, val);
    s += val;
  }
  pm[slot][d] = m;
  ps[slot][d] = s;
  __syncthreads();
  if (t < 64) {
    float mm = -INFINITY, ss = 0.f;
#pragma unroll
    for (int sl = 0; sl < 16; ++sl) {
      mm = fmaxf(mm, pm[sl][t]);
      ss += ps[sl][t];
    }
    pmax[(size_t)(base + bid) * 64 + t] = mm;
    psum[(size_t)(base + bid) * 64 + t] = ss;
  }
}

// ---------------- MLP + softmax (with deferred readout combine) ----------------

static __global__ void k_mlp(const float* __restrict__ pmax, const float* __restrict__ psum,
                             const float* __restrict__ lw1, const float* __restrict__ lb1,
                             const float* __restrict__ lw2, const float* __restrict__ lb2,
                             const float* __restrict__ lw3, const float* __restrict__ lb3,
                             float* __restrict__ out) {
  __shared__ float zs[128], t1[128], t2[64], t3[256], red[256];
  int b = blockIdx.x, tid = threadIdx.x;
  const int baseL[6] = {0, 512, 768, 896, 960, 992};
  const int nchL[6] = {32, 16, 8, 4, 2, 1};
  const int kkL[6] = {2048, 1024, 512, 256, 128, 64};
  if (tid < 64) {
    float zm = 0.f;
    for (int i = 0; i < 6; ++i) {
      float m = -INFINITY;
      for (int c = 0; c < nchL[i]; ++c)
        m = fmaxf(m, pmax[(size_t)(baseL[i] + b * nchL[i] + c) * 64 + tid]);
      zm += m;
    }
    zs[tid] = zm;
  } else if (tid < 128) {
    int d = tid - 64;
    float zsum = 0.f;
    for (int i = 0; i < 6; ++i) {
      float s = 0.f;
      for (int c = 0; c < nchL[i]; ++c)
        s += psum[(size_t)(baseL[i] + b * nchL[i] + c) * 64 + d];
      zsum += s / (float)kkL[i];
    }
    zs[tid] = zsum;
  }
  __syncthreads();
  if (tid < 128) {
    double a = 0.0;
    for (int d = 0; d < 128; ++d) a += (double)lw1[tid * 128 + d] * (double)zs[d];
    t1[tid] = fmaxf((float)a + lb1[tid], 0.0f);
  }
  __syncthreads();
  if (tid < 64) {
    double a = 0.0;
    for (int d = 0; d < 128; ++d) a += (double)lw2[tid * 128 + d] * (double)t1[d];
    t2[tid] = fmaxf((float)a + lb2[tid], 0.0f);
  }
  __syncthreads();
  {
    double a = 0.0;
    for (int d = 0; d < 64; ++d) a += (double)lw3[tid * 64 + d] * (double)t2[d];
    t3[tid] = (float)a + lb3[tid];
  }
  __syncthreads();
  red[tid] = t3[tid];
  __syncthreads();
  for (int s = 128; s > 0; s >>= 1) {
    if (tid < s) red[tid] = fmaxf(red[tid], red[tid + s]);
    __syncthreads();
  }
  float mx = red[0];
  __syncthreads();
  float e = expf(t3[tid] - mx);
  red[tid] = e;
  __syncthreads();
  for (int s = 128; s > 0; s >>= 1) {
    if (tid < s) red[tid] += red[tid + s];
    __syncthreads();
  }
  out[b * 256 + tid] = e / red[0];
}

// ---------------- launch ----------------

extern "C" void kernel_launch(void* const* d_in, const int* in_sizes, int n_in,
                              void* d_out, int out_size, void* d_ws, size_t ws_size,
                              hipStream_t stream) {
  const float* x0 = (const float*)d_in[0];
  const int* esrc0 = (const int*)d_in[1];
  const int* edst0 = (const int*)d_in[2];
  const float* WL[3] = {(const float*)d_in[3], (const float*)d_in[6], (const float*)d_in[9]};
  const float* BL[3] = {(const float*)d_in[4], (const float*)d_in[7], (const float*)d_in[10]};
  const float* WR[3] = {(const float*)d_in[5], (const float*)d_in[8], (const float*)d_in[11]};
  const float* WG[3] = {(const float*)d_in[12], (const float*)d_in[14], (const float*)d_in[16]};
  const float* BG[3] = {(const float*)d_in[13], (const float*)d_in[15], (const float*)d_in[17]};
  const float* P[6] = {(const float*)d_in[18], (const float*)d_in[19], (const float*)d_in[20],
                       (const float*)d_in[21], (const float*)d_in[22], (const float*)d_in[23]};
  const float* lw1 = (const float*)d_in[24];
  const float* lb1 = (const float*)d_in[25];
  const float* lw2 = (const float*)d_in[26];
  const float* lb2 = (const float*)d_in[27];
  const float* lw3 = (const float*)d_in[28];
  const float* lb3 = (const float*)d_in[29];

  char* ws = (char*)d_ws;
  size_t off = 0;
  auto alloc = [&](size_t bytes) -> void* {
    void* p = ws + off;
    off += (bytes + 255) & ~(size_t)255;
    return p;
  };
  float* hA = (float*)alloc((size_t)65536 * 64 * 4);
  float* hB = (float*)alloc((size_t)32768 * 64 * 4);
  float* tmp = (float*)alloc((size_t)8192 * 64 * 4);
  float* score = (float*)alloc((size_t)65536 * 4);
  int* newidx = (int*)alloc((size_t)65536 * 4);
  int* perm = (int*)alloc((size_t)32768 * 4);
  int* cntA = (int*)alloc((size_t)65536 * 4);
  int* cntB = (int*)alloc((size_t)65536 * 4);
  int* offsA = (int*)alloc((size_t)65536 * 4);
  int* offsB = (int*)alloc((size_t)65536 * 4);
  int* lenA = (int*)alloc((size_t)32768 * 4);
  int* lenB = (int*)alloc((size_t)32768 * 4);
  int* cursor = (int*)alloc((size_t)65536 * 4);
  int* bsum = (int*)alloc((size_t)64 * 4);
  int* listA = (int*)alloc((size_t)NE * 4);
  int* listB = (int*)alloc((size_t)NE * 4);
  float* pmax = (float*)alloc((size_t)1024 * 64 * 4);
  float* psum = (float*)alloc((size_t)1024 * 64 * 4);
  unsigned long long* keyA = (unsigned long long*)alloc((size_t)65536 * 8);
  unsigned long long* keyB = (unsigned long long*)alloc((size_t)65536 * 8);
  float* pnbuf = (float*)alloc((size_t)64 * 4);
  float* wp = (float*)alloc((size_t)7 * 4096 * 4);
  if (off > ws_size) return;  // workspace too small — bail

  auto scan = [&](int* cntp, int* offsp, int* curp, int n) {
    int nblk = (n + 1023) / 1024;
    k_scan1<<<nblk, 256, 0, stream>>>(cntp, offsp, bsum, n);
    k_scan3<<<(n + 255) / 256, 256, 0, stream>>>(offsp, curp, bsum, n, nblk);
  };

  k_pw<<<13, 256, 0, stream>>>(P[0], P[1], P[2], P[3], P[4], P[5], WL[1], WR[1], WL[2], WR[2],
                               WG[0], WG[1], WG[2], pnbuf, wp);

  // build layer-0 CSR (dst-sorted src lists)
  hipMemsetAsync(cntA, 0, (size_t)65536 * 4, stream);
  k_count<<<NE / 256, 256, 0, stream>>>(edst0, cntA);
  scan(cntA, offsA, cursor, 65536);
  k_fill0<<<NE / 256, 256, 0, stream>>>(esrc0, edst0, cursor, listA);

  const float* xcur = x0;
  int* ccnt = cntA;
  int* coffs = offsA;
  int* clist = listA;
  int* clen = nullptr;
  const int baseL[6] = {0, 512, 768, 896, 960, 992};

  for (int i = 0; i < 6; ++i) {
    int n_per = N0 >> i;
    int ntot = NB * n_per;
    int k = n_per >> 1;

    if (i == 0) {
      k_sage0<<<ntot / 64, 1024, 0, stream>>>(xcur, coffs, ccnt, clist, WL[0], BL[0], WR[0],
                                              P[0], pnbuf, hA, score);
    } else if (i < 3) {
      const float* wlp = wp + (size_t)((i - 1) * 2 + 0) * 4096;
      const float* wrp = wp + (size_t)((i - 1) * 2 + 1) * 4096;
      k_sage_mm<<<ntot / 64, 512, 0, stream>>>(xcur, coffs, ccnt, clist, wlp, BL[i], wrp, P[i],
                                               pnbuf, i, hA, score);
    } else {
      int g = i - 3;
      k_gcn_mm<<<ntot / 64, 256, 0, stream>>>(xcur, wp + (size_t)(4 + g) * 4096, tmp);
      k_gcn_gather<<<(ntot + 3) / 4, 256, 0, stream>>>(tmp, coffs, clen ? clen : ccnt, ccnt,
                                                       clist, BG[g], P[i], pnbuf, i, hA, score,
                                                       ntot);
    }

    // pool i: chunk sort (<=1024) + merge-path rounds
    int CH = (n_per < 1024) ? n_per : 1024;
    int single = (CH == n_per) ? 1 : 0;
    k_chunksort<<<ntot / CH, CH, (size_t)CH * 8, stream>>>(score, keyA, n_per, k, newidx, perm,
                                                           single);
    if (!single) {
      unsigned long long* cur = keyA;
      unsigned long long* nxt = keyB;
      for (int L = CH; L * 2 <= n_per; L <<= 1) {
        int fin = (L * 2 == n_per) ? 1 : 0;
        k_merge<<<(ntot + 255) / 256, 256, 0, stream>>>(cur, nxt, L, ntot, n_per, k, newidx, perm,
                                                        fin);
        unsigned long long* t2 = cur;
        cur = nxt;
        nxt = t2;
      }
    }

    int nch = k / 64;
    int G1 = NB * nch;
    int newn = (i < 5) ? NB * k : 0;
    int compacted_out = (i < 2);
    int sentinel_out = (i >= 2 && i < 5);
    int* ncnt = (i & 1) ? cntA : cntB;
    int* noffs = (i & 1) ? offsA : offsB;
    int* nlen = (i & 1) ? lenA : lenB;
    int* nlist = (i & 1) ? listA : listB;
    int G2 = (newn > 0) ? (newn + 1023) / 1024 : 0;
    int G3 = sentinel_out ? (NE / 1024) : 0;
    const int* lenarr = clen ? clen : ccnt;
    k_pool_post<<<G1 + G2 + G3, 1024, 0, stream>>>(
        hA, score, perm, hB, pmax, psum, baseL[i], coffs, lenarr, clist, newidx, ncnt,
        sentinel_out ? noffs : nullptr, sentinel_out ? nlen : nullptr, newn, G1, G2, clist,
        nlist, G3 ? NE : 0);

    if (compacted_out) {
      scan(ncnt, noffs, nullptr, newn);
      k_newfill<<<(newn + 255) / 256, 256, 0, stream>>>(perm, coffs, ccnt, clist, newidx, noffs,
                                                        nlist, newn);
      ccnt = ncnt;
      coffs = noffs;
      clist = nlist;
      clen = nullptr;
    } else if (sentinel_out) {
      ccnt = ncnt;
      coffs = noffs;
      clist = nlist;
      clen = nlen;
    }

    xcur = hB;
  }

  k_mlp<<<NB, 256, 0, stream>>>(pmax, psum, lw1, lb1, lw2, lb2, lw3, lb3, (float*)d_out);
}

// Round 17
// 337.941 us; speedup vs baseline: 1.0399x; 1.0059x over previous
//
#include <hip/hip_runtime.h>
#include <math.h>

#define NB 16
#define N0 4096
#define NE 524288
#define CAPE 1280

// ---------------- CSR build (layer 0, atomic int cursor only) ----------------

static __global__ void k_count(const int* __restrict__ dst, int* __restrict__ cnt) {
  int e = blockIdx.x * 256 + threadIdx.x;
  if (e >= NE) return;
  atomicAdd(&cnt[dst[e]], 1);
}

static __global__ void k_fill0(const int* __restrict__ src, const int* __restrict__ dst,
                               int* __restrict__ cursor, int* __restrict__ list) {
  int e = blockIdx.x * 256 + threadIdx.x;
  if (e >= NE) return;
  int d = dst[e];
  int slot = atomicAdd(&cursor[d], 1);
  list[slot] = src[e];
}

// ---------------- exclusive scan (scan1 + scan3-with-inline-bsum-prefix) ----------------

static __global__ void k_scan1(const int* __restrict__ in, int* __restrict__ out,
                               int* __restrict__ bsum, int n) {
  __shared__ int ts[256];
  int base = blockIdx.x * 1024 + threadIdx.x * 4;
  int a0 = (base + 0 < n) ? in[base + 0] : 0;
  int a1 = (base + 1 < n) ? in[base + 1] : 0;
  int a2 = (base + 2 < n) ? in[base + 2] : 0;
  int a3 = (base + 3 < n) ? in[base + 3] : 0;
  int s = a0 + a1 + a2 + a3;
  ts[threadIdx.x] = s;
  __syncthreads();
  for (int off = 1; off < 256; off <<= 1) {
    int v = (threadIdx.x >= off) ? ts[threadIdx.x - off] : 0;
    __syncthreads();
    ts[threadIdx.x] += v;
    __syncthreads();
  }
  int excl = ts[threadIdx.x] - s;
  if (base + 0 < n) out[base + 0] = excl;
  excl += a0;
  if (base + 1 < n) out[base + 1] = excl;
  excl += a1;
  if (base + 2 < n) out[base + 2] = excl;
  excl += a2;
  if (base + 3 < n) out[base + 3] = excl;
  if (threadIdx.x == 255) bsum[blockIdx.x] = ts[255];
}

static __global__ void k_scan3(int* __restrict__ out, int* __restrict__ out2,
                               const int* __restrict__ bsum, int n, int nblk) {
  __shared__ int sb[64];
  int t = threadIdx.x;
  if (t < 64) {
    int v = (t < nblk) ? bsum[t] : 0;
    int p = v;
    for (int off = 1; off < 64; off <<= 1) {
      int u = __shfl_up(p, off);
      if (t >= off) p += u;
    }
    sb[t] = p - v;
  }
  __syncthreads();
  int i = blockIdx.x * 256 + t;
  if (i < n) {
    int v = out[i] + sb[i >> 10];
    out[i] = v;
    if (out2) out2[i] = v;
  }
}

// ---------------- CSR compaction fill (pools 0,1 only) ----------------

static __global__ void k_newfill(const int* __restrict__ perm, const int* __restrict__ offs,
                                 const int* __restrict__ cnt, const int* __restrict__ list,
                                 const int* __restrict__ newidx, const int* __restrict__ noffs,
                                 int* __restrict__ nlist, int newn) {
  int nn = blockIdx.x * 256 + threadIdx.x;
  if (nn >= newn) return;
  int old = perm[nn];
  int st = offs[old], c = cnt[old];
  int pos = noffs[nn];
  for (int j = 0; j < c; ++j) {
    int s2 = newidx[list[st + j]];
    if (s2 >= 0) nlist[pos++] = s2;
  }
}

// ---------------- fused pnorm (blocks 0-5) + weight prep (blocks 6-12) ----------------

static __global__ void k_pw(const float* __restrict__ p0, const float* __restrict__ p1,
                            const float* __restrict__ p2, const float* __restrict__ p3,
                            const float* __restrict__ p4, const float* __restrict__ p5,
                            const float* __restrict__ w0, const float* __restrict__ w1,
                            const float* __restrict__ w2, const float* __restrict__ w3,
                            const float* __restrict__ w4, const float* __restrict__ w5,
                            const float* __restrict__ w6, float* __restrict__ pnbuf,
                            float* __restrict__ wp) {
  if (blockIdx.x < 6) {
    if (threadIdx.x >= 64) return;
    const float* pp = p0;
    switch (blockIdx.x) {
      case 1: pp = p1; break;
      case 2: pp = p2; break;
      case 3: pp = p3; break;
      case 4: pp = p4; break;
      case 5: pp = p5; break;
      default: break;
    }
    double v = (double)pp[threadIdx.x];
    v *= v;
#pragma unroll
    for (int off = 1; off < 64; off <<= 1) v += __shfl_xor(v, off);
    if (threadIdx.x == 0) pnbuf[blockIdx.x] = (float)(1.0 / sqrt(v));
  } else {
    int wi = blockIdx.x - 6;
    const float* src = w0;
    switch (wi) {
      case 1: src = w1; break;
      case 2: src = w2; break;
      case 3: src = w3; break;
      case 4: src = w4; break;
      case 5: src = w5; break;
      case 6: src = w6; break;
      default: break;
    }
    float* dst = wp + (size_t)wi * 4096;
    const float4* w4p = (const float4*)src;
    for (int i4 = threadIdx.x; i4 < 1024; i4 += 256) {
      int o = i4 >> 4, db = (i4 & 15) << 2;
      float4 W = w4p[i4];
      float Wv[4] = {W.x, W.y, W.z, W.w};
      int og = o >> 2, o3 = o & 3;
#pragma unroll
      for (int j = 0; j < 4; ++j) {
        int d = db + j;
        dst[(d << 6) + (((og ^ (d & 15)) << 2) | o3)] = Wv[j];
      }
    }
  }
}

// ---------------- SAGE layer 0 (DIN=2): fused mean + linear + relu + score ----------------

static __global__ __launch_bounds__(1024) void k_sage0(
    const float* __restrict__ x, const int* __restrict__ offs, const int* __restrict__ cnt,
    const int* __restrict__ list, const float* __restrict__ wl, const float* __restrict__ blv,
    const float* __restrict__ wr, const float* __restrict__ pvec,
    const float* __restrict__ pnbuf, float* __restrict__ h, float* __restrict__ score) {
  __shared__ float wlT[2][65], wrT[2][65];
  __shared__ float msh[64][2];
  int t = threadIdx.x;
  if (t < 128) {
    int o = t >> 1, d = t & 1;
    wlT[d][o] = wl[o * 2 + d];
    wrT[d][o] = wr[o * 2 + d];
  }
  if (t < 64) {
    int v = blockIdx.x * 64 + t;
    int st = offs[v], c = cnt[v];
    float s0 = 0.f, s1 = 0.f;
    for (int j = 0; j < c; ++j) {
      int s = list[st + j];
      s0 += x[s * 2 + 0];
      s1 += x[s * 2 + 1];
    }
    float inv = 1.0f / fmaxf((float)c, 1.0f);
    msh[t][0] = s0 * inv;
    msh[t][1] = s1 * inv;
  }
  __syncthreads();
  int o = t & 63, w = t >> 6;  // 16 waves
  float pn = pnbuf[0];
  float psl = pvec[o];
#pragma unroll
  for (int r = 0; r < 4; ++r) {
    int node = w * 4 + r;
    int v = blockIdx.x * 64 + node;
    float acc = blv[o] + msh[node][0] * wlT[0][o] + msh[node][1] * wlT[1][o] +
                x[v * 2 + 0] * wrT[0][o] + x[v * 2 + 1] * wrT[1][o];
    float hval = fmaxf(acc, 0.0f);
    h[(size_t)v * 64 + o] = hval;
    double sc = (double)hval * (double)psl;
#pragma unroll
    for (int off = 1; off < 64; off <<= 1) sc += __shfl_xor(sc, off);
    if (o == 0) score[v] = (float)sc * pn;
  }
}

// Fused SAGE DIN=64, 512 threads (8 waves), 64-node tile: XCD swizzle, LDS list
// staging, branchless j-unrolled (x2) 16-in-flight gather, 2x4 register-tile GEMM.
static __global__ __launch_bounds__(512) void k_sage_mm(
    const float* __restrict__ x, const int* __restrict__ offs, const int* __restrict__ cnt,
    const int* __restrict__ list, const float* __restrict__ wlT, const float* __restrict__ blv,
    const float* __restrict__ wrT, const float* __restrict__ pvec,
    const float* __restrict__ pnbuf, int pidx, float* __restrict__ h,
    float* __restrict__ score) {
  __shared__ float smem[8192];
  __shared__ float psh[64], bsh[64];
  __shared__ int lds_list[CAPE];
  float* xT = smem;
  float* mT = smem + 4096;
  int t = threadIdx.x;
  size_t nb = (size_t)((blockIdx.x & 7) * (gridDim.x >> 3) + (blockIdx.x >> 3));

  if (t < 64) {
    psh[t] = pvec[t];
    bsh[t] = blv[t];
  }
  const float4* x4 = (const float4*)(x + nb * 4096);
  for (int i = t; i < 1024; i += 512) {
    int node = i >> 4, db = (i & 15) << 2;
    float4 a = x4[i];
    float av[4] = {a.x, a.y, a.z, a.w};
    int ng = node >> 2, n0 = node & 3;
#pragma unroll
    for (int j = 0; j < 4; ++j) {
      int d = db + j;
      xT[(d << 6) + (((ng ^ (d & 15)) << 2) | n0)] = av[j];
    }
  }
  int gv0 = (int)nb * 64;
  int st0 = offs[gv0];
  int nedge = offs[gv0 + 63] + cnt[gv0 + 63] - st0;
  int ncap = (nedge < CAPE) ? nedge : CAPE;
  for (int e = t; e < ncap; e += 512) lds_list[e] = list[st0 + e];
  __syncthreads();

  {
    int lane = t & 63, w = t >> 6;
    int stq[8], cq[8];
    float accq[8];
    int cmax = 0;
#pragma unroll
    for (int q = 0; q < 8; ++q) {
      int gv = gv0 + w * 8 + q;
      stq[q] = offs[gv] - st0;
      cq[q] = cnt[gv];
      accq[q] = 0.f;
      cmax = max(cmax, cq[q]);
    }
    int ncl = (nedge > 0) ? (nedge - 1) : 0;
    int j = 0;
    for (; j + 1 < cmax; j += 2) {
#pragma unroll
      for (int q = 0; q < 8; ++q) {
        bool a0 = j < cq[q];
        bool a1 = (j + 1) < cq[q];
        int i0 = stq[q] + (a0 ? j : 0);
        int i1 = stq[q] + (a1 ? (j + 1) : 0);
        i0 = (i0 < ncl) ? i0 : ncl;
        i1 = (i1 < ncl) ? i1 : ncl;
        int s0 = (i0 < ncap) ? lds_list[i0] : list[st0 + i0];
        int s1 = (i1 < ncap) ? lds_list[i1] : list[st0 + i1];
        float xv0 = x[(size_t)(s0 & 32767) * 64 + lane];
        float xv1 = x[(size_t)(s1 & 32767) * 64 + lane];
        accq[q] = a0 ? (accq[q] + xv0) : accq[q];
        accq[q] = a1 ? (accq[q] + xv1) : accq[q];
      }
    }
    if (j < cmax) {
#pragma unroll
      for (int q = 0; q < 8; ++q) {
        bool act = j < cq[q];
        int idx = stq[q] + (act ? j : 0);
        idx = (idx < ncl) ? idx : ncl;
        int sn = (idx < ncap) ? lds_list[idx] : list[st0 + idx];
        float xv = x[(size_t)(sn & 32767) * 64 + lane];
        accq[q] = act ? (accq[q] + xv) : accq[q];
      }
    }
#pragma unroll
    for (int q = 0; q < 8; ++q) {
      int node = w * 8 + q;
      float mval = accq[q] * (1.0f / fmaxf((float)cq[q], 1.0f));
      int col = (((node >> 2) ^ (lane & 15)) << 2) | (node & 3);
      mT[(lane << 6) + col] = mval;
    }
  }
  __syncthreads();

  int tx = t & 15, ty = t >> 4;
  int ng = ty >> 1, n0 = (ty & 1) << 1;
  float acc[2][4] = {};
#pragma unroll 4
  for (int k = 0; k < 64; ++k) {
    int s = k & 15;
    int ca = (((ng ^ s) << 2) | n0);
    const float2 a2 = *(const float2*)&xT[(k << 6) + ca];
    const float2 m2 = *(const float2*)&mT[(k << 6) + ca];
    const float4 L = *(const float4*)&wlT[(k << 6) + ((tx ^ s) << 2)];
    const float4 R = *(const float4*)&wrT[(k << 6) + ((tx ^ s) << 2)];
    float A[2] = {a2.x, a2.y}, M[2] = {m2.x, m2.y};
    float Lv[4] = {L.x, L.y, L.z, L.w}, Rv[4] = {R.x, R.y, R.z, R.w};
#pragma unroll
    for (int r = 0; r < 2; ++r)
#pragma unroll
      for (int c = 0; c < 4; ++c) acc[r][c] += M[r] * Lv[c] + A[r] * Rv[c];
  }

  float pn = pnbuf[pidx];
  float hv[2][4];
  double sp[2];
#pragma unroll
  for (int r = 0; r < 2; ++r) {
    sp[r] = 0.0;
#pragma unroll
    for (int c = 0; c < 4; ++c) {
      float v = fmaxf(acc[r][c] + bsh[(tx << 2) + c], 0.0f);
      hv[r][c] = v;
      sp[r] += (double)v * (double)psh[(tx << 2) + c];
    }
  }
  __syncthreads();
  float* hT = smem;
  double* sred = (double*)(smem + 4608);
#pragma unroll
  for (int r = 0; r < 2; ++r) {
    int node = (ty << 1) + r;
    int nk = node & 15;
#pragma unroll
    for (int c = 0; c < 4; ++c) hT[node * 68 + (((tx ^ nk) << 2) | c)] = hv[r][c];
    sred[(tx << 6) + node] = sp[r];
  }
  __syncthreads();
  float4* h4 = (float4*)(h + nb * 4096);
  for (int i = t; i < 1024; i += 512) {
    int node = i >> 4, q = i & 15;
    h4[i] = *(const float4*)&hT[node * 68 + ((q ^ (node & 15)) << 2)];
  }
  if (t < 64) {
    double ssum = 0.0;
    for (int g = 0; g < 16; ++g) ssum += sred[(g << 6) + t];
    score[nb * 64 + t] = (float)ssum * pn;
  }
}

// ---------------- GCN ----------------

static __global__ __launch_bounds__(256) void k_gcn_mm(const float* __restrict__ x,
                                                       const float* __restrict__ wT,
                                                       float* __restrict__ h1) {
  __shared__ float smem[4608];
  float* xT = smem;
  int t = threadIdx.x;
  size_t nb = blockIdx.x;
  const float4* x4 = (const float4*)(x + nb * 4096);
  for (int i = t; i < 1024; i += 256) {
    int node = i >> 4, db = (i & 15) << 2;
    float4 a = x4[i];
    float av[4] = {a.x, a.y, a.z, a.w};
    int ng = node >> 2, n0 = node & 3;
#pragma unroll
    for (int j = 0; j < 4; ++j) {
      int d = db + j;
      xT[(d << 6) + (((ng ^ (d & 15)) << 2) | n0)] = av[j];
    }
  }
  __syncthreads();
  int tx = t & 15, ty = t >> 4;
  float acc[4][4] = {};
#pragma unroll 4
  for (int k = 0; k < 64; ++k) {
    int s = k & 15;
    const float4 a = *(const float4*)&xT[(k << 6) + ((tx ^ s) << 2)];
    const float4 W = *(const float4*)&wT[(k << 6) + ((ty ^ s) << 2)];
    float A[4] = {a.x, a.y, a.z, a.w}, Wv[4] = {W.x, W.y, W.z, W.w};
#pragma unroll
    for (int r = 0; r < 4; ++r)
#pragma unroll
      for (int c = 0; c < 4; ++c) acc[r][c] += A[r] * Wv[c];
  }
  __syncthreads();
  float* hT = smem;
#pragma unroll
  for (int r = 0; r < 4; ++r) {
    int node = (tx << 2) + r;
    int nk = node & 15;
#pragma unroll
    for (int c = 0; c < 4; ++c) hT[node * 68 + (((ty ^ nk) << 2) | c)] = acc[r][c];
  }
  __syncthreads();
  float4* h4 = (float4*)(h1 + nb * 4096);
  for (int i = t; i < 1024; i += 256) {
    int node = i >> 4, q = i & 15;
    h4[i] = *(const float4*)&hT[node * 68 + ((q ^ (node & 15)) << 2)];
  }
}

// sentinel-CSR gather, j-unrolled x2 (clamped unconditional loads, ordered adds)
static __global__ void k_gcn_gather(const float* __restrict__ h1, const int* __restrict__ offs,
                                    const int* __restrict__ lenarr, const int* __restrict__ vcnt,
                                    const int* __restrict__ list, const float* __restrict__ b,
                                    const float* __restrict__ pvec,
                                    const float* __restrict__ pnbuf, int pidx,
                                    float* __restrict__ h, float* __restrict__ score, int ntot) {
  int lane = threadIdx.x & 63, vl = threadIdx.x >> 6;
  int v = blockIdx.x * 4 + vl;
  if (v >= ntot) return;
  int st = offs[v], len = lenarr[v];
  float degv = 1.0f + (float)vcnt[v];
  float ivd = 1.0f / sqrtf(degv);
  float acc = 0.f;
  int j = 0;
  for (; j + 1 < len; j += 2) {
    int e0 = list[st + j];
    int e1 = list[st + j + 1];
    int c0 = (e0 >= 0) ? e0 : 0;
    int c1 = (e1 >= 0) ? e1 : 0;
    float n0 = (1.0f / sqrtf(1.0f + (float)vcnt[c0])) * ivd;
    float n1 = (1.0f / sqrtf(1.0f + (float)vcnt[c1])) * ivd;
    float v0 = h1[(size_t)c0 * 64 + lane];
    float v1 = h1[(size_t)c1 * 64 + lane];
    acc = (e0 >= 0) ? (acc + v0 * n0) : acc;
    acc = (e1 >= 0) ? (acc + v1 * n1) : acc;
  }
  if (j < len) {
    int e0 = list[st + j];
    if (e0 >= 0) {
      float nrm = (1.0f / sqrtf(1.0f + (float)vcnt[e0])) * ivd;
      acc += h1[(size_t)e0 * 64 + lane] * nrm;
    }
  }
  float outv = fmaxf(acc + h1[(size_t)v * 64 + lane] * (1.0f / degv) + b[lane], 0.0f);
  h[(size_t)v * 64 + lane] = outv;
  double sc = (double)outv * (double)pvec[lane];
#pragma unroll
  for (int off = 1; off < 64; off <<= 1) sc += __shfl_xor(sc, off);
  if (lane == 0) score[v] = (float)sc * pnbuf[pidx];
}

// ---------------- TopK pool: chunk bitonic (<=1024) + merge-path ----------------

static __global__ void k_chunksort(const float* __restrict__ score,
                                   unsigned long long* __restrict__ runs, int n_per, int k,
                                   int* __restrict__ newidx, int* __restrict__ perm, int single) {
  extern __shared__ unsigned long long sk[];
  int CH = blockDim.x;
  int g0 = blockIdx.x * CH;
  int b = g0 / n_per;
  int i = threadIdx.x;
  int gi = g0 + i;
  int li = gi - b * n_per;
  unsigned u = __float_as_uint(score[gi]);
  unsigned s = (u & 0x80000000u) ? u : ~(u | 0x80000000u);
  sk[i] = ((unsigned long long)s << 32) | (unsigned)li;
  __syncthreads();
  for (int ksz = 2; ksz <= CH; ksz <<= 1) {
    for (int j = ksz >> 1; j > 0; j >>= 1) {
      int ixj = i ^ j;
      if (ixj > i) {
        unsigned long long a = sk[i], c = sk[ixj];
        bool up = ((i & ksz) == 0);
        if ((a > c) == up) {
          sk[i] = c;
          sk[ixj] = a;
        }
      }
      __syncthreads();
    }
  }
  if (!single) {
    runs[gi] = sk[i];
  } else {
    int r = i;
    int idx = (int)(sk[r] & 0xFFFFFFFFu);
    int gidx = b * n_per + idx;
    if (r < k) {
      perm[b * k + r] = gidx;
      newidx[gidx] = b * k + r;
    } else {
      newidx[gidx] = -1;
    }
  }
}

static __global__ void k_merge(const unsigned long long* __restrict__ in,
                               unsigned long long* __restrict__ out, int L, int ntot, int n_per,
                               int k, int* __restrict__ newidx, int* __restrict__ perm,
                               int final) {
  int g = blockIdx.x * 256 + threadIdx.x;
  if (g >= ntot) return;
  unsigned long long key = in[g];
  int pair = g / (2 * L);
  int base = pair * 2 * L;
  int t = g - base;
  const unsigned long long* sib;
  int p;
  if (t < L) {
    sib = in + base + L;
    p = t;
  } else {
    sib = in + base;
    p = t - L;
  }
  int lo = 0, hi = L;
  while (lo < hi) {
    int mid = (lo + hi) >> 1;
    lo = (sib[mid] < key) ? mid + 1 : lo;
    hi = (sib[mid] < key) ? hi : mid;
  }
  int pos = p + lo;
  if (!final) {
    out[base + pos] = key;
  } else {
    int b = base / n_per;
    int idx = (int)(key & 0xFFFFFFFFu);
    int gidx = b * n_per + idx;
    if (pos < k) {
      perm[b * k + pos] = gidx;
      newidx[gidx] = b * k + pos;
    } else {
      newidx[gidx] = -1;
    }
  }
}

// ---------------- pool_post: gather_ro | vcnt-count | flat remap ----------------

static __global__ __launch_bounds__(1024) void k_pool_post(
    const float* __restrict__ h, const float* __restrict__ score, const int* __restrict__ perm,
    float* __restrict__ xnew, float* __restrict__ pmax, float* __restrict__ psum, int base,
    const int* __restrict__ offs, const int* __restrict__ lenarr, const int* __restrict__ list,
    const int* __restrict__ newidx, int* __restrict__ ncnt, int* __restrict__ noffs,
    int* __restrict__ nlen, int newn, int G1, int G2, const int* __restrict__ rin,
    int* __restrict__ rout, int rn) {
  __shared__ float tile[64 * 68];
  __shared__ float pm[16][65], ps[16][65];
  int t = threadIdx.x;
  int bid = blockIdx.x;
  if (bid >= G1 + G2) {
    int e = (bid - G1 - G2) * 1024 + t;
    if (e < rn) {
      int v = rin[e];
      rout[e] = (v >= 0 && v < 65536) ? newidx[v] : -1;
    }
    return;
  }
  if (bid >= G1) {
    int nn = (bid - G1) * 1024 + t;
    if (nn >= newn) return;
    int old = perm[nn];
    int st = offs[old], c = lenarr[old];
    int cc = 0;
    for (int j = 0; j < c; ++j) {
      int e = list[st + j];
      cc += (e >= 0 && newidx[e] >= 0);
    }
    ncnt[nn] = cc;
    return;
  }
  int node = t >> 4, q = t & 15;
  int nn = bid * 64 + node;
  int old = perm[nn];
  if (noffs && t < 64) {
    int nn2 = bid * 64 + t;
    int o2 = perm[nn2];
    noffs[nn2] = offs[o2];
    nlen[nn2] = lenarr[o2];
  }
  float tm = tanhf(score[old]);
  float4 v = *(const float4*)&h[(size_t)old * 64 + q * 4];
  v.x *= tm;
  v.y *= tm;
  v.z *= tm;
  v.w *= tm;
  *(float4*)&xnew[(size_t)nn * 64 + q * 4] = v;
  *(float4*)&tile[node * 68 + ((q ^ (node & 15)) << 2)] = v;
  __syncthreads();
  int slot = t >> 6, d = t & 63;
  int q2 = d >> 2, i3 = d & 3;
  float m = -INFINITY, s = 0.f;
#pragma unroll
  for (int r = 0; r < 4; ++r) {
    int nd = slot * 4 + r;
    float val = tile[nd * 68 + (((q2 ^ (nd & 15)) << 2) | i3)];
    m = fmaxf(m, val);
    s += val;
  }
  pm[slot][d] = m;
  ps[slot][d] = s;
  __syncthreads();
  if (t < 64) {
    float mm = -INFINITY, ss = 0.f;
#pragma unroll
    for (int sl = 0; sl < 16; ++sl) {
      mm = fmaxf(mm, pm[sl][t]);
      ss += ps[sl][t];
    }
    pmax[(size_t)(base + bid) * 64 + t] = mm;
    psum[(size_t)(base + bid) * 64 + t] = ss;
  }
}

// ---------------- MLP + softmax (with deferred readout combine) ----------------

static __global__ void k_mlp(const float* __restrict__ pmax, const float* __restrict__ psum,
                             const float* __restrict__ lw1, const float* __restrict__ lb1,
                             const float* __restrict__ lw2, const float* __restrict__ lb2,
                             const float* __restrict__ lw3, const float* __restrict__ lb3,
                             float* __restrict__ out) {
  __shared__ float zs[128], t1[128], t2[64], t3[256], red[256];
  int b = blockIdx.x, tid = threadIdx.x;
  const int baseL[6] = {0, 512, 768, 896, 960, 992};
  const int nchL[6] = {32, 16, 8, 4, 2, 1};
  const int kkL[6] = {2048, 1024, 512, 256, 128, 64};
  if (tid < 64) {
    float zm = 0.f;
    for (int i = 0; i < 6; ++i) {
      float m = -INFINITY;
      for (int c = 0; c < nchL[i]; ++c)
        m = fmaxf(m, pmax[(size_t)(baseL[i] + b * nchL[i] + c) * 64 + tid]);
      zm += m;
    }
    zs[tid] = zm;
  } else if (tid < 128) {
    int d = tid - 64;
    float zsum = 0.f;
    for (int i = 0; i < 6; ++i) {
      float s = 0.f;
      for (int c = 0; c < nchL[i]; ++c)
        s += psum[(size_t)(baseL[i] + b * nchL[i] + c) * 64 + d];
      zsum += s / (float)kkL[i];
    }
    zs[tid] = zsum;
  }
  __syncthreads();
  if (tid < 128) {
    double a = 0.0;
    for (int d = 0; d < 128; ++d) a += (double)lw1[tid * 128 + d] * (double)zs[d];
    t1[tid] = fmaxf((float)a + lb1[tid], 0.0f);
  }
  __syncthreads();
  if (tid < 64) {
    double a = 0.0;
    for (int d = 0; d < 128; ++d) a += (double)lw2[tid * 128 + d] * (double)t1[d];
    t2[tid] = fmaxf((float)a + lb2[tid], 0.0f);
  }
  __syncthreads();
  {
    double a = 0.0;
    for (int d = 0; d < 64; ++d) a += (double)lw3[tid * 64 + d] * (double)t2[d];
    t3[tid] = (float)a + lb3[tid];
  }
  __syncthreads();
  red[tid] = t3[tid];
  __syncthreads();
  for (int s = 128; s > 0; s >>= 1) {
    if (tid < s) red[tid] = fmaxf(red[tid], red[tid + s]);
    __syncthreads();
  }
  float mx = red[0];
  __syncthreads();
  float e = expf(t3[tid] - mx);
  red[tid] = e;
  __syncthreads();
  for (int s = 128; s > 0; s >>= 1) {
    if (tid < s) red[tid] += red[tid + s];
    __syncthreads();
  }
  out[b * 256 + tid] = e / red[0];
}

// ---------------- launch ----------------

extern "C" void kernel_launch(void* const* d_in, const int* in_sizes, int n_in,
                              void* d_out, int out_size, void* d_ws, size_t ws_size,
                              hipStream_t stream) {
  const float* x0 = (const float*)d_in[0];
  const int* esrc0 = (const int*)d_in[1];
  const int* edst0 = (const int*)d_in[2];
  const float* WL[3] = {(const float*)d_in[3], (const float*)d_in[6], (const float*)d_in[9]};
  const float* BL[3] = {(const float*)d_in[4], (const float*)d_in[7], (const float*)d_in[10]};
  const float* WR[3] = {(const float*)d_in[5], (const float*)d_in[8], (const float*)d_in[11]};
  const float* WG[3] = {(const float*)d_in[12], (const float*)d_in[14], (const float*)d_in[16]};
  const float* BG[3] = {(const float*)d_in[13], (const float*)d_in[15], (const float*)d_in[17]};
  const float* P[6] = {(const float*)d_in[18], (const float*)d_in[19], (const float*)d_in[20],
                       (const float*)d_in[21], (const float*)d_in[22], (const float*)d_in[23]};
  const float* lw1 = (const float*)d_in[24];
  const float* lb1 = (const float*)d_in[25];
  const float* lw2 = (const float*)d_in[26];
  const float* lb2 = (const float*)d_in[27];
  const float* lw3 = (const float*)d_in[28];
  const float* lb3 = (const float*)d_in[29];

  char* ws = (char*)d_ws;
  size_t off = 0;
  auto alloc = [&](size_t bytes) -> void* {
    void* p = ws + off;
    off += (bytes + 255) & ~(size_t)255;
    return p;
  };
  float* hA = (float*)alloc((size_t)65536 * 64 * 4);
  float* hB = (float*)alloc((size_t)32768 * 64 * 4);
  float* tmp = (float*)alloc((size_t)8192 * 64 * 4);
  float* score = (float*)alloc((size_t)65536 * 4);
  int* newidx = (int*)alloc((size_t)65536 * 4);
  int* perm = (int*)alloc((size_t)32768 * 4);
  int* cntA = (int*)alloc((size_t)65536 * 4);
  int* cntB = (int*)alloc((size_t)65536 * 4);
  int* offsA = (int*)alloc((size_t)65536 * 4);
  int* offsB = (int*)alloc((size_t)65536 * 4);
  int* lenA = (int*)alloc((size_t)32768 * 4);
  int* lenB = (int*)alloc((size_t)32768 * 4);
  int* cursor = (int*)alloc((size_t)65536 * 4);
  int* bsum = (int*)alloc((size_t)64 * 4);
  int* listA = (int*)alloc((size_t)NE * 4);
  int* listB = (int*)alloc((size_t)NE * 4);
  float* pmax = (float*)alloc((size_t)1024 * 64 * 4);
  float* psum = (float*)alloc((size_t)1024 * 64 * 4);
  unsigned long long* keyA = (unsigned long long*)alloc((size_t)65536 * 8);
  unsigned long long* keyB = (unsigned long long*)alloc((size_t)65536 * 8);
  float* pnbuf = (float*)alloc((size_t)64 * 4);
  float* wp = (float*)alloc((size_t)7 * 4096 * 4);
  if (off > ws_size) return;  // workspace too small — bail

  auto scan = [&](int* cntp, int* offsp, int* curp, int n) {
    int nblk = (n + 1023) / 1024;
    k_scan1<<<nblk, 256, 0, stream>>>(cntp, offsp, bsum, n);
    k_scan3<<<(n + 255) / 256, 256, 0, stream>>>(offsp, curp, bsum, n, nblk);
  };

  k_pw<<<13, 256, 0, stream>>>(P[0], P[1], P[2], P[3], P[4], P[5], WL[1], WR[1], WL[2], WR[2],
                               WG[0], WG[1], WG[2], pnbuf, wp);

  // build layer-0 CSR (dst-sorted src lists)
  hipMemsetAsync(cntA, 0, (size_t)65536 * 4, stream);
  k_count<<<NE / 256, 256, 0, stream>>>(edst0, cntA);
  scan(cntA, offsA, cursor, 65536);
  k_fill0<<<NE / 256, 256, 0, stream>>>(esrc0, edst0, cursor, listA);

  const float* xcur = x0;
  int* ccnt = cntA;
  int* coffs = offsA;
  int* clist = listA;
  int* clen = nullptr;
  const int baseL[6] = {0, 512, 768, 896, 960, 992};

  for (int i = 0; i < 6; ++i) {
    int n_per = N0 >> i;
    int ntot = NB * n_per;
    int k = n_per >> 1;

    if (i == 0) {
      k_sage0<<<ntot / 64, 1024, 0, stream>>>(xcur, coffs, ccnt, clist, WL[0], BL[0], WR[0],
                                              P[0], pnbuf, hA, score);
    } else if (i < 3) {
      const float* wlp = wp + (size_t)((i - 1) * 2 + 0) * 4096;
      const float* wrp = wp + (size_t)((i - 1) * 2 + 1) * 4096;
      k_sage_mm<<<ntot / 64, 512, 0, stream>>>(xcur, coffs, ccnt, clist, wlp, BL[i], wrp, P[i],
                                               pnbuf, i, hA, score);
    } else {
      int g = i - 3;
      k_gcn_mm<<<ntot / 64, 256, 0, stream>>>(xcur, wp + (size_t)(4 + g) * 4096, tmp);
      k_gcn_gather<<<(ntot + 3) / 4, 256, 0, stream>>>(tmp, coffs, clen ? clen : ccnt, ccnt,
                                                       clist, BG[g], P[i], pnbuf, i, hA, score,
                                                       ntot);
    }

    // pool i: chunk sort (<=1024) + merge-path rounds
    int CH = (n_per < 1024) ? n_per : 1024;
    int single = (CH == n_per) ? 1 : 0;
    k_chunksort<<<ntot / CH, CH, (size_t)CH * 8, stream>>>(score, keyA, n_per, k, newidx, perm,
                                                           single);
    if (!single) {
      unsigned long long* cur = keyA;
      unsigned long long* nxt = keyB;
      for (int L = CH; L * 2 <= n_per; L <<= 1) {
        int fin = (L * 2 == n_per) ? 1 : 0;
        k_merge<<<(ntot + 255) / 256, 256, 0, stream>>>(cur, nxt, L, ntot, n_per, k, newidx, perm,
                                                        fin);
        unsigned long long* t2 = cur;
        cur = nxt;
        nxt = t2;
      }
    }

    int nch = k / 64;
    int G1 = NB * nch;
    int newn = (i < 5) ? NB * k : 0;
    int compacted_out = (i < 2);
    int sentinel_out = (i >= 2 && i < 5);
    int* ncnt = (i & 1) ? cntA : cntB;
    int* noffs = (i & 1) ? offsA : offsB;
    int* nlen = (i & 1) ? lenA : lenB;
    int* nlist = (i & 1) ? listA : listB;
    int G2 = (newn > 0) ? (newn + 1023) / 1024 : 0;
    int G3 = sentinel_out ? (NE / 1024) : 0;
    const int* lenarr = clen ? clen : ccnt;
    k_pool_post<<<G1 + G2 + G3, 1024, 0, stream>>>(
        hA, score, perm, hB, pmax, psum, baseL[i], coffs, lenarr, clist, newidx, ncnt,
        sentinel_out ? noffs : nullptr, sentinel_out ? nlen : nullptr, newn, G1, G2, clist,
        nlist, G3 ? NE : 0);

    if (compacted_out) {
      scan(ncnt, noffs, nullptr, newn);
      k_newfill<<<(newn + 255) / 256, 256, 0, stream>>>(perm, coffs, ccnt, clist, newidx, noffs,
                                                        nlist, newn);
      ccnt = ncnt;
      coffs = noffs;
      clist = nlist;
      clen = nullptr;
    } else if (sentinel_out) {
      ccnt = ncnt;
      coffs = noffs;
      clist = nlist;
      clen = nlen;
    }

    xcur = hB;
  }

  k_mlp<<<NB, 256, 0, stream>>>(pmax, psum, lw1, lb1, lw2, lb2, lw3, lb3, (float*)d_out);
}